// Round 2
// baseline (701.120 us; speedup 1.0000x reference)
//
#include <hip/hip_runtime.h>

#define N_NODES 100000
#define N_EDGES 1000000
#define NB_SCAN 391  /* ceil(N/256) */
#define EDGE_OUT_BASE 1200000  /* N_NODES*12 elements */

typedef __attribute__((ext_vector_type(8))) short short8;
typedef __attribute__((ext_vector_type(4))) float f32x4;

__device__ __forceinline__ float bf2f(unsigned short u) {
    unsigned int x = ((unsigned int)u) << 16;
    return __builtin_bit_cast(float, x);
}
__device__ __forceinline__ unsigned short f2bf(float f) {
    unsigned int x = __builtin_bit_cast(unsigned int, f);
    return (unsigned short)((x + 0x7fffu + ((x >> 16) & 1u)) >> 16);
}

// ---------------- dtype detection ----------------
// True bf16 N(0,1): no element has exponent field >= 148 (|v| >= 2^21).
// f32 read as ushorts: low halves have uniform exponent bits -> ~42% >= 148.
__global__ __launch_bounds__(256) void k_detect(const unsigned short* __restrict__ xr,
                                                int* __restrict__ flag) {
    __shared__ int s[256];
    int t = threadIdx.x;
    int cnt = 0;
    for (int i = t; i < 8192; i += 256) {
        int e = (xr[i] >> 7) & 0xFF;
        if (e >= 148) cnt++;
    }
    s[t] = cnt;
    __syncthreads();
    for (int off = 128; off > 0; off >>= 1) {
        if (t < off) s[t] += s[t + off];
        __syncthreads();
    }
    if (t == 0) *flag = (s[0] > 100) ? 1 : 0;
}

// ---------------- weight canonicalization (any dtype -> bf16) ----------------
struct WPack { const void* p[14]; };
#define W_TOTAL 87888
__global__ __launch_bounds__(256) void k_convw(WPack wp, const int* __restrict__ flag,
                                               unsigned short* __restrict__ dst) {
    const int starts[15] = {0, 8192, 8320, 24704, 24832, 41216, 41344, 49536,
                            49600, 50368, 50380, 87244, 87372, 87884, 87888};
    bool f32 = (*flag != 0);
    int i = blockIdx.x * 256 + threadIdx.x;
    if (i >= W_TOTAL) return;
    int s = 0;
#pragma unroll
    for (int k = 1; k < 14; k++) s += (i >= starts[k]) ? 1 : 0;
    int j = i - starts[s];
    dst[i] = f32 ? f2bf(((const float*)wp.p[s])[j]) : ((const unsigned short*)wp.p[s])[j];
}
// canonical offsets
#define OW_We 0
#define OW_be 8192
#define OW_Wc1 8320
#define OW_bc1 24704
#define OW_Wc2 24832
#define OW_bc2 41216
#define OW_Wn1 41344
#define OW_bn1 49536
#define OW_Wn2 49600
#define OW_bn2 50368
#define OW_We1 50380
#define OW_be1 87244
#define OW_We2 87372
#define OW_be2 87884

// ---------------- graph build ----------------
__global__ __launch_bounds__(256) void k_hist(const int* __restrict__ ecol, int* __restrict__ deg) {
    int e = blockIdx.x * 256 + threadIdx.x;
    if (e < N_EDGES) atomicAdd(&deg[ecol[e]], 1);
}

__global__ __launch_bounds__(256) void k_scanA(const int* __restrict__ deg, int* __restrict__ bsum) {
    __shared__ int s[256];
    int i = blockIdx.x * 256 + threadIdx.x;
    s[threadIdx.x] = (i < N_NODES) ? deg[i] : 0;
    __syncthreads();
    for (int off = 128; off > 0; off >>= 1) {
        if (threadIdx.x < off) s[threadIdx.x] += s[threadIdx.x + off];
        __syncthreads();
    }
    if (threadIdx.x == 0) bsum[blockIdx.x] = s[0];
}

__global__ __launch_bounds__(512) void k_scanB(int* __restrict__ bsum) {
    __shared__ int s[512];
    int t = threadIdx.x;
    int v = (t < NB_SCAN) ? bsum[t] : 0;
    s[t] = v;
    __syncthreads();
    for (int off = 1; off < 512; off <<= 1) {
        int x = (t >= off) ? s[t - off] : 0;
        __syncthreads();
        s[t] += x;
        __syncthreads();
    }
    if (t < NB_SCAN) bsum[t] = s[t] - v;  // exclusive
}

__global__ __launch_bounds__(256) void k_scanC(const int* __restrict__ deg, const int* __restrict__ bsum,
                                               int* __restrict__ row_off, int* __restrict__ cursor,
                                               float* __restrict__ dinv) {
    __shared__ int s[256];
    int i = blockIdx.x * 256 + threadIdx.x;
    int t = threadIdx.x;
    int v = (i < N_NODES) ? deg[i] : 0;
    s[t] = v;
    __syncthreads();
    for (int off = 1; off < 256; off <<= 1) {
        int x = (t >= off) ? s[t - off] : 0;
        __syncthreads();
        s[t] += x;
        __syncthreads();
    }
    int excl = s[t] - v + bsum[blockIdx.x];
    if (i < N_NODES) {
        row_off[i] = excl;
        cursor[i] = excl;
        dinv[i] = rsqrtf((float)(v + 1));  // +1 self-loop
    }
    if (i == N_NODES - 1) row_off[N_NODES] = excl + v;
}

__global__ __launch_bounds__(256) void k_fill(const int* __restrict__ erow, const int* __restrict__ ecol,
                                              int* __restrict__ cursor, int* __restrict__ csr) {
    int e = blockIdx.x * 256 + threadIdx.x;
    if (e < N_EDGES) {
        int pos = atomicAdd(&cursor[ecol[e]], 1);
        csr[pos] = erow[e];
    }
}

// ---------------- rows GEMM: Out[M,o_real] = act(A[M,K] @ W[K,o_real] + bias) ----------------
// A dtype: bf16, or f32 if (aflag && *aflag). Out: bf16 ws buffer, or output buffer
// whose dtype follows (oflag && *oflag). In-place (Out==A) is safe: each wave reads
// only its own 32 rows, fully, before storing.
template <int K, int O, bool RELU, bool BIAS>
__global__ __launch_bounds__(256) void gemm_rows(const void* __restrict__ A, int M,
                                                 const unsigned short* __restrict__ W, int o_real,
                                                 const unsigned short* __restrict__ bias,
                                                 void* __restrict__ Out, int out_pitch,
                                                 const int* aflag, const int* oflag) {
    constexpr int KP = K + 8;  // padded LDS pitch (bf16)
    constexpr int KS = K / 32;
    constexpr int OT = O / 16;
    __shared__ short wt[O * KP];  // W transposed: wt[o][k]
    __shared__ float bias_s[O];
    int tid = threadIdx.x;
    for (int idx = tid; idx < K * O; idx += 256) {
        int k = idx / O, o = idx % O;
        short w = 0;
        if (o < o_real) w = (short)W[(size_t)k * o_real + o];
        wt[o * KP + k] = w;
    }
    if (BIAS) {
        for (int o = tid; o < O; o += 256) bias_s[o] = (o < o_real) ? bf2f(bias[o]) : 0.f;
    }
    __syncthreads();

    bool af32 = aflag && (*aflag != 0);
    bool of32 = oflag && (*oflag != 0);

    int wid = tid >> 6, lane = tid & 63;
    int rbase = (blockIdx.x * 4 + wid) * 32;
    if (rbase >= M) return;
    int lq = lane >> 4, lr = lane & 15;

    short8 a[2][KS];
#pragma unroll
    for (int rg = 0; rg < 2; rg++) {
        int row = rbase + rg * 16 + lr;
        if (row >= M) row = M - 1;
        if (af32) {
            const float* ap = (const float*)A + (size_t)row * K + lq * 8;
#pragma unroll
            for (int ks = 0; ks < KS; ks++) {
                f32x4 u0 = *(const f32x4*)(ap + ks * 32);
                f32x4 u1 = *(const f32x4*)(ap + ks * 32 + 4);
                short8 v;
                v[0] = (short)f2bf(u0[0]); v[1] = (short)f2bf(u0[1]);
                v[2] = (short)f2bf(u0[2]); v[3] = (short)f2bf(u0[3]);
                v[4] = (short)f2bf(u1[0]); v[5] = (short)f2bf(u1[1]);
                v[6] = (short)f2bf(u1[2]); v[7] = (short)f2bf(u1[3]);
                a[rg][ks] = v;
            }
        } else {
            const unsigned short* ap = (const unsigned short*)A + (size_t)row * K + lq * 8;
#pragma unroll
            for (int ks = 0; ks < KS; ks++) a[rg][ks] = *(const short8*)(ap + ks * 32);
        }
    }

    f32x4 acc[2][OT];
#pragma unroll
    for (int rg = 0; rg < 2; rg++)
#pragma unroll
        for (int j = 0; j < OT; j++) {
            acc[rg][j][0] = 0.f; acc[rg][j][1] = 0.f; acc[rg][j][2] = 0.f; acc[rg][j][3] = 0.f;
        }

#pragma unroll
    for (int j = 0; j < OT; j++) {
        short8 b[KS];
#pragma unroll
        for (int ks = 0; ks < KS; ks++)
            b[ks] = *(const short8*)(&wt[(lr + 16 * j) * KP + ks * 32 + lq * 8]);
#pragma unroll
        for (int rg = 0; rg < 2; rg++)
#pragma unroll
            for (int ks = 0; ks < KS; ks++)
                acc[rg][j] = __builtin_amdgcn_mfma_f32_16x16x32_bf16(a[rg][ks], b[ks], acc[rg][j], 0, 0, 0);
    }

    // D layout: col = lane&15, row = (lane>>4)*4 + reg   [measured m89/m91]
#pragma unroll
    for (int rg = 0; rg < 2; rg++)
#pragma unroll
        for (int j = 0; j < OT; j++)
#pragma unroll
            for (int r = 0; r < 4; r++) {
                int row = rbase + rg * 16 + lq * 4 + r;
                int col = lr + 16 * j;
                if (row < M && col < o_real) {
                    float v = acc[rg][j][r];
                    if (BIAS) v += bias_s[col];
                    if (RELU) v = fmaxf(v, 0.f);
                    size_t oi = (size_t)row * out_pitch + col;
                    if (of32) ((float*)Out)[oi] = v;
                    else ((unsigned short*)Out)[oi] = f2bf(v);
                }
            }
}

// ---------------- GCN scatter/gather conv: one wave per node ----------------
__global__ __launch_bounds__(256) void conv_kernel(const unsigned short* __restrict__ xw,
                                                   const int* __restrict__ csr_src,
                                                   const int* __restrict__ row_off,
                                                   const float* __restrict__ dinv,
                                                   const unsigned short* __restrict__ bias,
                                                   unsigned short* __restrict__ out) {
    int wid = threadIdx.x >> 6, lane = threadIdx.x & 63;
    int t = blockIdx.x * 4 + wid;  // N divisible by 4
    int beg = row_off[t], end = row_off[t + 1];
    float dt = dinv[t];
    unsigned int v = *(const unsigned int*)(xw + (size_t)t * 128 + lane * 2);
    float w_self = dt * dt;
    float acc0 = bf2f((unsigned short)(v & 0xffff)) * w_self;
    float acc1 = bf2f((unsigned short)(v >> 16)) * w_self;
    for (int i = beg; i < end; i++) {
        int s = csr_src[i];
        float w = dinv[s] * dt;
        unsigned int u = *(const unsigned int*)(xw + (size_t)s * 128 + lane * 2);
        acc0 = fmaf(bf2f((unsigned short)(u & 0xffff)), w, acc0);
        acc1 = fmaf(bf2f((unsigned short)(u >> 16)), w, acc1);
    }
    acc0 = fmaxf(acc0 + bf2f(bias[lane * 2]), 0.f);
    acc1 = fmaxf(acc1 + bf2f(bias[lane * 2 + 1]), 0.f);
    unsigned int o = (unsigned int)f2bf(acc0) | ((unsigned int)f2bf(acc1) << 16);
    *(unsigned int*)(out + (size_t)t * 128 + lane * 2) = o;
}

// ---------------- fused edge head ----------------
// out[e] = relu(P[row]+Q[col]+ea@Wc3+b1) @ W2 + b2,  Wc3 = Wedge1 rows 256..287
__global__ __launch_bounds__(256) void edge_head(const void* __restrict__ ea,
                                                 const int* __restrict__ erow, const int* __restrict__ ecol,
                                                 const unsigned short* __restrict__ P,
                                                 const unsigned short* __restrict__ Q,
                                                 const unsigned short* __restrict__ wbuf,
                                                 void* __restrict__ out, const int* dtflag) {
    __shared__ short wct[128 * 40];  // Wc3 transposed [col][k], pitch 40 bf16
    __shared__ float w2s[128 * 4];
    __shared__ float b1s[128];
    __shared__ float b2s[4];
    __shared__ float T[4][16 * 132];  // per-wave [16 edges][128 ch], pitch 132 f32
    int tid = threadIdx.x;
    const unsigned short* Wc3 = wbuf + OW_We1 + 256 * 128;
    for (int idx = tid; idx < 32 * 128; idx += 256) {
        int k = idx >> 7, o = idx & 127;
        wct[o * 40 + k] = (short)Wc3[idx];
    }
    for (int idx = tid; idx < 512; idx += 256) w2s[idx] = bf2f(wbuf[OW_We2 + idx]);
    if (tid < 128) b1s[tid] = bf2f(wbuf[OW_be1 + tid]);
    if (tid < 4) b2s[tid] = bf2f(wbuf[OW_be2 + tid]);
    __syncthreads();

    bool f32io = (*dtflag != 0);
    int wid = tid >> 6, lane = tid & 63;
    int e0 = (blockIdx.x * 4 + wid) * 16;  // E divisible by 64
    int lq = lane >> 4, lr = lane & 15;

    // R[16 edges x 128 ch] = ea_tile[16x32] @ Wc3[32x128]
    short8 afrag;
    if (f32io) {
        const float* eap = (const float*)ea + (size_t)(e0 + lr) * 32 + lq * 8;
        f32x4 u0 = *(const f32x4*)eap;
        f32x4 u1 = *(const f32x4*)(eap + 4);
        afrag[0] = (short)f2bf(u0[0]); afrag[1] = (short)f2bf(u0[1]);
        afrag[2] = (short)f2bf(u0[2]); afrag[3] = (short)f2bf(u0[3]);
        afrag[4] = (short)f2bf(u1[0]); afrag[5] = (short)f2bf(u1[1]);
        afrag[6] = (short)f2bf(u1[2]); afrag[7] = (short)f2bf(u1[3]);
    } else {
        afrag = *(const short8*)((const unsigned short*)ea + (size_t)(e0 + lr) * 32 + lq * 8);
    }
    f32x4 zero; zero[0] = 0.f; zero[1] = 0.f; zero[2] = 0.f; zero[3] = 0.f;
    f32x4 acc[8];
#pragma unroll
    for (int j = 0; j < 8; j++) {
        short8 b = *(const short8*)(&wct[(lr + 16 * j) * 40 + lq * 8]);
        acc[j] = __builtin_amdgcn_mfma_f32_16x16x32_bf16(afrag, b, zero, 0, 0, 0);
    }
    float* Tw = T[wid];
#pragma unroll
    for (int j = 0; j < 8; j++)
#pragma unroll
        for (int r = 0; r < 4; r++)
            Tw[(lq * 4 + r) * 132 + lr + 16 * j] = acc[j][r];
    __syncthreads();

    // epilogue: 4 lanes per edge, 32 channels per lane
    int e = lane >> 2, part = lane & 3;
    int ge = e0 + e;
    int rn = erow[ge], cn = ecol[ge];
    const float* trow = Tw + e * 132 + part * 32;
    const unsigned short* Pp = P + (size_t)rn * 128 + part * 32;
    const unsigned short* Qp = Q + (size_t)cn * 128 + part * 32;
    float o0 = 0.f, o1 = 0.f, o2 = 0.f, o3 = 0.f;
#pragma unroll
    for (int blk = 0; blk < 4; blk++) {
        short8 pv = *(const short8*)(Pp + blk * 8);
        short8 qv = *(const short8*)(Qp + blk * 8);
#pragma unroll
        for (int i = 0; i < 8; i++) {
            int ch = part * 32 + blk * 8 + i;
            float tval = trow[blk * 8 + i] + bf2f((unsigned short)pv[i]) + bf2f((unsigned short)qv[i]) + b1s[ch];
            tval = fmaxf(tval, 0.f);
            o0 = fmaf(tval, w2s[ch * 4 + 0], o0);
            o1 = fmaf(tval, w2s[ch * 4 + 1], o1);
            o2 = fmaf(tval, w2s[ch * 4 + 2], o2);
            o3 = fmaf(tval, w2s[ch * 4 + 3], o3);
        }
    }
    o0 += __shfl_xor(o0, 1); o0 += __shfl_xor(o0, 2);
    o1 += __shfl_xor(o1, 1); o1 += __shfl_xor(o1, 2);
    o2 += __shfl_xor(o2, 1); o2 += __shfl_xor(o2, 2);
    o3 += __shfl_xor(o3, 1); o3 += __shfl_xor(o3, 2);
    float res = (part == 0) ? o0 : (part == 1) ? o1 : (part == 2) ? o2 : o3;
    res += b2s[part];
    size_t oi = (size_t)EDGE_OUT_BASE + (size_t)ge * 4 + part;
    if (f32io) ((float*)out)[oi] = res;
    else ((unsigned short*)out)[oi] = f2bf(res);
}

// ---------------- launcher ----------------
extern "C" void kernel_launch(void* const* d_in, const int* in_sizes, int n_in,
                              void* d_out, int out_size, void* d_ws, size_t ws_size,
                              hipStream_t stream) {
    const void* x = d_in[0];
    const int* ei = (const int*)d_in[1];
    const void* ea = d_in[2];
    const int* erow = ei;
    const int* ecol = ei + N_EDGES;

    char* ws = (char*)d_ws;
    size_t off = 0;
    auto alloc = [&](size_t bytes) -> void* {
        void* p = ws + off;
        off += (bytes + 255) & ~(size_t)255;
        return p;
    };
    unsigned short* Abuf = (unsigned short*)alloc((size_t)N_NODES * 128 * 2);
    unsigned short* Bbuf = (unsigned short*)alloc((size_t)N_NODES * 128 * 2);
    int* deg = (int*)alloc((size_t)N_NODES * 4);
    int* row_off = (int*)alloc((size_t)(N_NODES + 1) * 4);
    int* cursor = (int*)alloc((size_t)N_NODES * 4);
    int* csr = (int*)alloc((size_t)N_EDGES * 4);
    int* bsum = (int*)alloc(512 * 4);
    float* dinv = (float*)alloc((size_t)N_NODES * 4);
    unsigned short* wbuf = (unsigned short*)alloc((size_t)W_TOTAL * 2);
    int* dtflag = (int*)alloc(256);
    // total ws use: ~57.1 MB

    // 1. dtype detection (device-side; host cannot branch on data under graph capture)
    k_detect<<<1, 256, 0, stream>>>((const unsigned short*)x, dtflag);

    // 2. canonicalize all weights/biases to bf16
    WPack wp;
    for (int i = 0; i < 14; i++) wp.p[i] = d_in[3 + i];
    k_convw<<<(W_TOTAL + 255) / 256, 256, 0, stream>>>(wp, dtflag, wbuf);

    // 3. graph build (once, reused by both convs)
    hipMemsetAsync(deg, 0, (size_t)N_NODES * 4, stream);
    k_hist<<<(N_EDGES + 255) / 256, 256, 0, stream>>>(ecol, deg);
    k_scanA<<<NB_SCAN, 256, 0, stream>>>(deg, bsum);
    k_scanB<<<1, 512, 0, stream>>>(bsum);
    k_scanC<<<NB_SCAN, 256, 0, stream>>>(deg, bsum, row_off, cursor, dinv);
    k_fill<<<(N_EDGES + 255) / 256, 256, 0, stream>>>(erow, ecol, cursor, csr);

    int gB = (N_NODES + 127) / 128;
    // embed: h0 = relu(x@We+be)  (double relu idempotent); x dtype via flag
    gemm_rows<64, 128, true, true><<<gB, 256, 0, stream>>>(x, N_NODES, wbuf + OW_We, 128, wbuf + OW_be, Abuf, 128, dtflag, nullptr);
    // conv1
    gemm_rows<128, 128, false, false><<<gB, 256, 0, stream>>>(Abuf, N_NODES, wbuf + OW_Wc1, 128, nullptr, Bbuf, 128, nullptr, nullptr);
    conv_kernel<<<N_NODES / 4, 256, 0, stream>>>(Bbuf, csr, row_off, dinv, wbuf + OW_bc1, Abuf);
    // conv2
    gemm_rows<128, 128, false, false><<<gB, 256, 0, stream>>>(Abuf, N_NODES, wbuf + OW_Wc2, 128, nullptr, Bbuf, 128, nullptr, nullptr);
    conv_kernel<<<N_NODES / 4, 256, 0, stream>>>(Bbuf, csr, row_off, dinv, wbuf + OW_bc2, Abuf);
    // node head: z = relu(h@Wn1+bn1) -> Bbuf(pitch 64); logits = z@Wn2+bn2 -> out (dtype via flag)
    gemm_rows<128, 64, true, true><<<gB, 256, 0, stream>>>(Abuf, N_NODES, wbuf + OW_Wn1, 64, wbuf + OW_bn1, Bbuf, 64, nullptr, nullptr);
    gemm_rows<64, 16, false, true><<<gB, 256, 0, stream>>>(Bbuf, N_NODES, wbuf + OW_Wn2, 12, wbuf + OW_bn2, d_out, 12, nullptr, dtflag);
    // edge head precompute: P = h@W_a -> Bbuf;  Q = h@W_b -> Abuf (in-place safe)
    gemm_rows<128, 128, false, false><<<gB, 256, 0, stream>>>(Abuf, N_NODES, wbuf + OW_We1, 128, nullptr, Bbuf, 128, nullptr, nullptr);
    gemm_rows<128, 128, false, false><<<gB, 256, 0, stream>>>(Abuf, N_NODES, wbuf + OW_We1 + 128 * 128, 128, nullptr, Abuf, 128, nullptr, nullptr);
    // fused edge head: P=Bbuf, Q=Abuf
    edge_head<<<N_EDGES / 64, 256, 0, stream>>>(ea, erow, ecol, Bbuf, Abuf, wbuf, d_out, dtflag);
}

// Round 3
// 661.387 us; speedup vs baseline: 1.0601x; 1.0601x over previous
//
#include <hip/hip_runtime.h>

#define N_NODES 100000
#define N_EDGES 1000000
#define NB_SCAN 391  /* ceil(N/256) */
#define EDGE_OUT_BASE 1200000  /* N_NODES*12 elements */

typedef __attribute__((ext_vector_type(8))) short short8;
typedef __attribute__((ext_vector_type(4))) float f32x4;

__device__ __forceinline__ float bf2f(unsigned short u) {
    unsigned int x = ((unsigned int)u) << 16;
    return __builtin_bit_cast(float, x);
}
__device__ __forceinline__ float lo_bf(unsigned int u) {
    return __builtin_bit_cast(float, u << 16);
}
__device__ __forceinline__ float hi_bf(unsigned int u) {
    return __builtin_bit_cast(float, u & 0xffff0000u);
}
__device__ __forceinline__ unsigned short f2bf(float f) {
    unsigned int x = __builtin_bit_cast(unsigned int, f);
    return (unsigned short)((x + 0x7fffu + ((x >> 16) & 1u)) >> 16);
}

// ---------------- dtype detection ----------------
__global__ __launch_bounds__(256) void k_detect(const unsigned short* __restrict__ xr,
                                                int* __restrict__ flag) {
    __shared__ int s[256];
    int t = threadIdx.x;
    int cnt = 0;
    for (int i = t; i < 8192; i += 256) {
        int e = (xr[i] >> 7) & 0xFF;
        if (e >= 148) cnt++;
    }
    s[t] = cnt;
    __syncthreads();
    for (int off = 128; off > 0; off >>= 1) {
        if (t < off) s[t] += s[t + off];
        __syncthreads();
    }
    if (t == 0) *flag = (s[0] > 100) ? 1 : 0;
}

// ---------------- weight canonicalization (any dtype -> bf16) ----------------
struct WPack { const void* p[14]; };
#define W_TOTAL 87888
__global__ __launch_bounds__(256) void k_convw(WPack wp, const int* __restrict__ flag,
                                               unsigned short* __restrict__ dst) {
    const int starts[15] = {0, 8192, 8320, 24704, 24832, 41216, 41344, 49536,
                            49600, 50368, 50380, 87244, 87372, 87884, 87888};
    bool f32 = (*flag != 0);
    int i = blockIdx.x * 256 + threadIdx.x;
    if (i >= W_TOTAL) return;
    int s = 0;
#pragma unroll
    for (int k = 1; k < 14; k++) s += (i >= starts[k]) ? 1 : 0;
    int j = i - starts[s];
    dst[i] = f32 ? f2bf(((const float*)wp.p[s])[j]) : ((const unsigned short*)wp.p[s])[j];
}
#define OW_We 0
#define OW_be 8192
#define OW_Wc1 8320
#define OW_bc1 24704
#define OW_Wc2 24832
#define OW_bc2 41216
#define OW_Wn1 41344
#define OW_bn1 49536
#define OW_Wn2 49600
#define OW_bn2 50368
#define OW_We1 50380
#define OW_be1 87244
#define OW_We2 87372
#define OW_be2 87884

// ---------------- graph build ----------------
__global__ __launch_bounds__(256) void k_hist(const int* __restrict__ ecol, int* __restrict__ deg) {
    int e = blockIdx.x * 256 + threadIdx.x;
    if (e < N_EDGES) atomicAdd(&deg[ecol[e]], 1);
}

__global__ __launch_bounds__(256) void k_scanA(const int* __restrict__ deg, int* __restrict__ bsum) {
    __shared__ int s[256];
    int i = blockIdx.x * 256 + threadIdx.x;
    s[threadIdx.x] = (i < N_NODES) ? deg[i] : 0;
    __syncthreads();
    for (int off = 128; off > 0; off >>= 1) {
        if (threadIdx.x < off) s[threadIdx.x] += s[threadIdx.x + off];
        __syncthreads();
    }
    if (threadIdx.x == 0) bsum[blockIdx.x] = s[0];
}

__global__ __launch_bounds__(512) void k_scanB(int* __restrict__ bsum) {
    __shared__ int s[512];
    int t = threadIdx.x;
    int v = (t < NB_SCAN) ? bsum[t] : 0;
    s[t] = v;
    __syncthreads();
    for (int off = 1; off < 512; off <<= 1) {
        int x = (t >= off) ? s[t - off] : 0;
        __syncthreads();
        s[t] += x;
        __syncthreads();
    }
    if (t < NB_SCAN) bsum[t] = s[t] - v;  // exclusive
}

__global__ __launch_bounds__(256) void k_scanC(const int* __restrict__ deg, const int* __restrict__ bsum,
                                               int* __restrict__ row_off, int* __restrict__ cursor,
                                               float* __restrict__ dinv) {
    __shared__ int s[256];
    int i = blockIdx.x * 256 + threadIdx.x;
    int t = threadIdx.x;
    int v = (i < N_NODES) ? deg[i] : 0;
    s[t] = v;
    __syncthreads();
    for (int off = 1; off < 256; off <<= 1) {
        int x = (t >= off) ? s[t - off] : 0;
        __syncthreads();
        s[t] += x;
        __syncthreads();
    }
    int excl = s[t] - v + bsum[blockIdx.x];
    if (i < N_NODES) {
        row_off[i] = excl;
        cursor[i] = excl;
        dinv[i] = rsqrtf((float)(v + 1));  // +1 self-loop
    }
    if (i == N_NODES - 1) row_off[N_NODES] = excl + v;
}

__global__ __launch_bounds__(256) void k_fill(const int* __restrict__ erow, const int* __restrict__ ecol,
                                              int* __restrict__ cursor, int* __restrict__ csr) {
    int e = blockIdx.x * 256 + threadIdx.x;
    if (e < N_EDGES) {
        int pos = atomicAdd(&cursor[ecol[e]], 1);
        csr[pos] = erow[e];
    }
}

// ---------------- rows GEMM: Out[M,o_real] = act(A[M,K] @ W[K,o_real] + bias) [* rowscale] ----------------
template <int K, int O, bool RELU, bool BIAS, bool SCALE>
__global__ __launch_bounds__(256) void gemm_rows(const void* __restrict__ A, int M,
                                                 const unsigned short* __restrict__ W, int o_real,
                                                 const unsigned short* __restrict__ bias,
                                                 void* __restrict__ Out, int out_pitch,
                                                 const float* __restrict__ rowscale,
                                                 const int* aflag, const int* oflag) {
    constexpr int KP = K + 8;
    constexpr int KS = K / 32;
    constexpr int OT = O / 16;
    __shared__ short wt[O * KP];
    __shared__ float bias_s[O];
    int tid = threadIdx.x;
    for (int idx = tid; idx < K * O; idx += 256) {
        int k = idx / O, o = idx % O;
        short w = 0;
        if (o < o_real) w = (short)W[(size_t)k * o_real + o];
        wt[o * KP + k] = w;
    }
    if (BIAS) {
        for (int o = tid; o < O; o += 256) bias_s[o] = (o < o_real) ? bf2f(bias[o]) : 0.f;
    }
    __syncthreads();

    bool af32 = aflag && (*aflag != 0);
    bool of32 = oflag && (*oflag != 0);

    int wid = tid >> 6, lane = tid & 63;
    int rbase = (blockIdx.x * 4 + wid) * 32;
    if (rbase >= M) return;
    int lq = lane >> 4, lr = lane & 15;

    short8 a[2][KS];
#pragma unroll
    for (int rg = 0; rg < 2; rg++) {
        int row = rbase + rg * 16 + lr;
        if (row >= M) row = M - 1;
        if (af32) {
            const float* ap = (const float*)A + (size_t)row * K + lq * 8;
#pragma unroll
            for (int ks = 0; ks < KS; ks++) {
                f32x4 u0 = *(const f32x4*)(ap + ks * 32);
                f32x4 u1 = *(const f32x4*)(ap + ks * 32 + 4);
                short8 v;
                v[0] = (short)f2bf(u0[0]); v[1] = (short)f2bf(u0[1]);
                v[2] = (short)f2bf(u0[2]); v[3] = (short)f2bf(u0[3]);
                v[4] = (short)f2bf(u1[0]); v[5] = (short)f2bf(u1[1]);
                v[6] = (short)f2bf(u1[2]); v[7] = (short)f2bf(u1[3]);
                a[rg][ks] = v;
            }
        } else {
            const unsigned short* ap = (const unsigned short*)A + (size_t)row * K + lq * 8;
#pragma unroll
            for (int ks = 0; ks < KS; ks++) a[rg][ks] = *(const short8*)(ap + ks * 32);
        }
    }

    f32x4 acc[2][OT];
#pragma unroll
    for (int rg = 0; rg < 2; rg++)
#pragma unroll
        for (int j = 0; j < OT; j++) {
            acc[rg][j][0] = 0.f; acc[rg][j][1] = 0.f; acc[rg][j][2] = 0.f; acc[rg][j][3] = 0.f;
        }

#pragma unroll
    for (int j = 0; j < OT; j++) {
        short8 b[KS];
#pragma unroll
        for (int ks = 0; ks < KS; ks++)
            b[ks] = *(const short8*)(&wt[(lr + 16 * j) * KP + ks * 32 + lq * 8]);
#pragma unroll
        for (int rg = 0; rg < 2; rg++)
#pragma unroll
            for (int ks = 0; ks < KS; ks++)
                acc[rg][j] = __builtin_amdgcn_mfma_f32_16x16x32_bf16(a[rg][ks], b[ks], acc[rg][j], 0, 0, 0);
    }

    // D layout: col = lane&15, row = (lane>>4)*4 + reg
#pragma unroll
    for (int rg = 0; rg < 2; rg++)
#pragma unroll
        for (int j = 0; j < OT; j++)
#pragma unroll
            for (int r = 0; r < 4; r++) {
                int row = rbase + rg * 16 + lq * 4 + r;
                int col = lr + 16 * j;
                if (row < M && col < o_real) {
                    float v = acc[rg][j][r];
                    if (BIAS) v += bias_s[col];
                    if (RELU) v = fmaxf(v, 0.f);
                    if (SCALE) v *= rowscale[row];
                    size_t oi = (size_t)row * out_pitch + col;
                    if (of32) ((float*)Out)[oi] = v;
                    else ((unsigned short*)Out)[oi] = f2bf(v);
                }
            }
}

// ---------------- dual GEMM for edge-head P/Q (O=128 x2, K=128) ----------------
// P = A @ W1 -> Pout ; Q = A @ W2 -> Qout (Qout may alias A: all A reads precede stores)
__global__ __launch_bounds__(256) void gemm_pq(const unsigned short* __restrict__ A, int M,
                                               const unsigned short* __restrict__ W1,
                                               const unsigned short* __restrict__ W2,
                                               unsigned short* __restrict__ Pout,
                                               unsigned short* __restrict__ Qout) {
    __shared__ short wt[128 * 136];
    int tid = threadIdx.x;
    int wid = tid >> 6, lane = tid & 63;
    int rbase = (blockIdx.x * 4 + wid) * 32;
    int lq = lane >> 4, lr = lane & 15;

    // A fragments (once)
    short8 a[2][4];
#pragma unroll
    for (int rg = 0; rg < 2; rg++) {
        int row = rbase + rg * 16 + lr;
        if (row >= M) row = M - 1;
        const unsigned short* ap = A + (size_t)row * 128 + lq * 8;
#pragma unroll
        for (int ks = 0; ks < 4; ks++) a[rg][ks] = *(const short8*)(ap + ks * 32);
    }

    f32x4 acc[2][2][8];  // [which][rg][j]
#pragma unroll
    for (int w = 0; w < 2; w++)
#pragma unroll
        for (int rg = 0; rg < 2; rg++)
#pragma unroll
            for (int j = 0; j < 8; j++) {
                acc[w][rg][j][0] = 0.f; acc[w][rg][j][1] = 0.f;
                acc[w][rg][j][2] = 0.f; acc[w][rg][j][3] = 0.f;
            }

    const unsigned short* Ws[2] = {W1, W2};
#pragma unroll 1
    for (int w = 0; w < 2; w++) {
        __syncthreads();  // prev phase done reading wt
        for (int idx = tid; idx < 128 * 128; idx += 256) {
            int k = idx >> 7, o = idx & 127;
            wt[o * 136 + k] = (short)Ws[w][idx];
        }
        __syncthreads();
#pragma unroll
        for (int j = 0; j < 8; j++) {
            short8 b[4];
#pragma unroll
            for (int ks = 0; ks < 4; ks++)
                b[ks] = *(const short8*)(&wt[(lr + 16 * j) * 136 + ks * 32 + lq * 8]);
#pragma unroll
            for (int rg = 0; rg < 2; rg++)
#pragma unroll
                for (int ks = 0; ks < 4; ks++)
                    acc[w][rg][j] = __builtin_amdgcn_mfma_f32_16x16x32_bf16(a[rg][ks], b[ks], acc[w][rg][j], 0, 0, 0);
        }
    }

    if (rbase >= M) return;
#pragma unroll
    for (int w = 0; w < 2; w++) {
        unsigned short* Out = w ? Qout : Pout;
#pragma unroll
        for (int rg = 0; rg < 2; rg++)
#pragma unroll
            for (int j = 0; j < 8; j++)
#pragma unroll
                for (int r = 0; r < 4; r++) {
                    int row = rbase + rg * 16 + lq * 4 + r;
                    int col = lr + 16 * j;
                    if (row < M) Out[(size_t)row * 128 + col] = f2bf(acc[w][rg][j][r]);
                }
    }
}

// ---------------- GCN conv: prescaled input, unroll-4 gather-sum ----------------
// in: xw_s[s] = (h@W)[s] * dinv[s].  out[t] = relu(dinv[t]*(sum_{s in N(t)} xw_s[s] + xw_s[t]) + bias)
__global__ __launch_bounds__(256) void conv_kernel(const unsigned short* __restrict__ xw_s,
                                                   const int* __restrict__ csr_src,
                                                   const int* __restrict__ row_off,
                                                   const float* __restrict__ dinv,
                                                   const unsigned short* __restrict__ bias,
                                                   unsigned short* __restrict__ out) {
    int wid = threadIdx.x >> 6, lane = threadIdx.x & 63;
    int t = blockIdx.x * 4 + wid;  // N divisible by 4
    int beg = row_off[t], end = row_off[t + 1];
    float dt = dinv[t];
    unsigned int v = *(const unsigned int*)(xw_s + (size_t)t * 128 + lane * 2);
    unsigned int bv = *(const unsigned int*)(bias + lane * 2);
    float a0 = lo_bf(v), a1 = hi_bf(v);
    int i = beg;
    for (; i + 4 <= end; i += 4) {
        int s0 = csr_src[i], s1 = csr_src[i + 1], s2 = csr_src[i + 2], s3 = csr_src[i + 3];
        unsigned int u0 = *(const unsigned int*)(xw_s + (size_t)s0 * 128 + lane * 2);
        unsigned int u1 = *(const unsigned int*)(xw_s + (size_t)s1 * 128 + lane * 2);
        unsigned int u2 = *(const unsigned int*)(xw_s + (size_t)s2 * 128 + lane * 2);
        unsigned int u3 = *(const unsigned int*)(xw_s + (size_t)s3 * 128 + lane * 2);
        a0 += lo_bf(u0) + lo_bf(u1) + lo_bf(u2) + lo_bf(u3);
        a1 += hi_bf(u0) + hi_bf(u1) + hi_bf(u2) + hi_bf(u3);
    }
    for (; i < end; i++) {
        int s = csr_src[i];
        unsigned int u = *(const unsigned int*)(xw_s + (size_t)s * 128 + lane * 2);
        a0 += lo_bf(u);
        a1 += hi_bf(u);
    }
    a0 = fmaxf(fmaf(a0, dt, lo_bf(bv)), 0.f);
    a1 = fmaxf(fmaf(a1, dt, hi_bf(bv)), 0.f);
    unsigned int o = (unsigned int)f2bf(a0) | ((unsigned int)f2bf(a1) << 16);
    *(unsigned int*)(out + (size_t)t * 128 + lane * 2) = o;
}

// ---------------- fused edge head (bf16 T tile, pitch 136) ----------------
__global__ __launch_bounds__(256) void edge_head(const void* __restrict__ ea,
                                                 const int* __restrict__ erow, const int* __restrict__ ecol,
                                                 const unsigned short* __restrict__ P,
                                                 const unsigned short* __restrict__ Q,
                                                 const unsigned short* __restrict__ wbuf,
                                                 void* __restrict__ out, const int* dtflag) {
    __shared__ short wct[128 * 40];          // Wc3^T [ch][k], pitch 40
    __shared__ float w2s[128 * 4];
    __shared__ float b1s[128];
    __shared__ float b2s[4];
    __shared__ unsigned short Tb[4][16 * 136];  // per-wave [16 edges][128 ch] bf16, pitch 136
    int tid = threadIdx.x;
    const unsigned short* Wc3 = wbuf + OW_We1 + 256 * 128;
    for (int idx = tid; idx < 32 * 128; idx += 256) {
        int k = idx >> 7, o = idx & 127;
        wct[o * 40 + k] = (short)Wc3[idx];
    }
    for (int idx = tid; idx < 512; idx += 256) w2s[idx] = bf2f(wbuf[OW_We2 + idx]);
    if (tid < 128) b1s[tid] = bf2f(wbuf[OW_be1 + tid]);
    if (tid < 4) b2s[tid] = bf2f(wbuf[OW_be2 + tid]);
    __syncthreads();

    bool f32io = (*dtflag != 0);
    int wid = tid >> 6, lane = tid & 63;
    int e0 = (blockIdx.x * 4 + wid) * 16;
    int lq = lane >> 4, lr = lane & 15;

    // R[16 edges x 128 ch] = ea_tile[16x32] @ Wc3[32x128]
    short8 afrag;
    if (f32io) {
        const float* eap = (const float*)ea + (size_t)(e0 + lr) * 32 + lq * 8;
        f32x4 u0 = *(const f32x4*)eap;
        f32x4 u1 = *(const f32x4*)(eap + 4);
        afrag[0] = (short)f2bf(u0[0]); afrag[1] = (short)f2bf(u0[1]);
        afrag[2] = (short)f2bf(u0[2]); afrag[3] = (short)f2bf(u0[3]);
        afrag[4] = (short)f2bf(u1[0]); afrag[5] = (short)f2bf(u1[1]);
        afrag[6] = (short)f2bf(u1[2]); afrag[7] = (short)f2bf(u1[3]);
    } else {
        afrag = *(const short8*)((const unsigned short*)ea + (size_t)(e0 + lr) * 32 + lq * 8);
    }
    f32x4 zero; zero[0] = 0.f; zero[1] = 0.f; zero[2] = 0.f; zero[3] = 0.f;
    f32x4 acc[8];
#pragma unroll
    for (int j = 0; j < 8; j++) {
        short8 b = *(const short8*)(&wct[(lr + 16 * j) * 40 + lq * 8]);
        acc[j] = __builtin_amdgcn_mfma_f32_16x16x32_bf16(afrag, b, zero, 0, 0, 0);
    }
    unsigned short* Tw = Tb[wid];
#pragma unroll
    for (int j = 0; j < 8; j++)
#pragma unroll
        for (int r = 0; r < 4; r++)
            Tw[(lq * 4 + r) * 136 + lr + 16 * j] = f2bf(acc[j][r]);
    __syncthreads();

    // epilogue: 4 lanes per edge, 32 channels per lane
    int e = lane >> 2, part = lane & 3;
    int ge = e0 + e;
    int rn = erow[ge], cn = ecol[ge];
    const unsigned short* trow = Tw + e * 136 + part * 32;
    const unsigned short* Pp = P + (size_t)rn * 128 + part * 32;
    const unsigned short* Qp = Q + (size_t)cn * 128 + part * 32;
    float o0 = 0.f, o1 = 0.f, o2 = 0.f, o3 = 0.f;
#pragma unroll
    for (int blk = 0; blk < 4; blk++) {
        short8 pv = *(const short8*)(Pp + blk * 8);
        short8 qv = *(const short8*)(Qp + blk * 8);
        short8 tv = *(const short8*)(trow + blk * 8);
#pragma unroll
        for (int i = 0; i < 8; i++) {
            int ch = part * 32 + blk * 8 + i;
            float tval = bf2f((unsigned short)tv[i]) + bf2f((unsigned short)pv[i]) +
                         bf2f((unsigned short)qv[i]) + b1s[ch];
            tval = fmaxf(tval, 0.f);
            o0 = fmaf(tval, w2s[ch * 4 + 0], o0);
            o1 = fmaf(tval, w2s[ch * 4 + 1], o1);
            o2 = fmaf(tval, w2s[ch * 4 + 2], o2);
            o3 = fmaf(tval, w2s[ch * 4 + 3], o3);
        }
    }
    o0 += __shfl_xor(o0, 1); o0 += __shfl_xor(o0, 2);
    o1 += __shfl_xor(o1, 1); o1 += __shfl_xor(o1, 2);
    o2 += __shfl_xor(o2, 1); o2 += __shfl_xor(o2, 2);
    o3 += __shfl_xor(o3, 1); o3 += __shfl_xor(o3, 2);
    float res = (part == 0) ? o0 : (part == 1) ? o1 : (part == 2) ? o2 : o3;
    res += b2s[part];
    size_t oi = (size_t)EDGE_OUT_BASE + (size_t)ge * 4 + part;
    if (f32io) ((float*)out)[oi] = res;
    else ((unsigned short*)out)[oi] = f2bf(res);
}

// ---------------- launcher ----------------
extern "C" void kernel_launch(void* const* d_in, const int* in_sizes, int n_in,
                              void* d_out, int out_size, void* d_ws, size_t ws_size,
                              hipStream_t stream) {
    const void* x = d_in[0];
    const int* ei = (const int*)d_in[1];
    const void* ea = d_in[2];
    const int* erow = ei;
    const int* ecol = ei + N_EDGES;

    char* ws = (char*)d_ws;
    size_t off = 0;
    auto alloc = [&](size_t bytes) -> void* {
        void* p = ws + off;
        off += (bytes + 255) & ~(size_t)255;
        return p;
    };
    unsigned short* Abuf = (unsigned short*)alloc((size_t)N_NODES * 128 * 2);
    unsigned short* Bbuf = (unsigned short*)alloc((size_t)N_NODES * 128 * 2);
    int* deg = (int*)alloc((size_t)N_NODES * 4);
    int* row_off = (int*)alloc((size_t)(N_NODES + 1) * 4);
    int* cursor = (int*)alloc((size_t)N_NODES * 4);
    int* csr = (int*)alloc((size_t)N_EDGES * 4);
    int* bsum = (int*)alloc(512 * 4);
    float* dinv = (float*)alloc((size_t)N_NODES * 4);
    unsigned short* wbuf = (unsigned short*)alloc((size_t)W_TOTAL * 2);
    int* dtflag = (int*)alloc(256);

    // 1. dtype detection (device-side)
    k_detect<<<1, 256, 0, stream>>>((const unsigned short*)x, dtflag);

    // 2. canonicalize weights to bf16
    WPack wp;
    for (int i = 0; i < 14; i++) wp.p[i] = d_in[3 + i];
    k_convw<<<(W_TOTAL + 255) / 256, 256, 0, stream>>>(wp, dtflag, wbuf);

    // 3. graph build
    hipMemsetAsync(deg, 0, (size_t)N_NODES * 4, stream);
    k_hist<<<(N_EDGES + 255) / 256, 256, 0, stream>>>(ecol, deg);
    k_scanA<<<NB_SCAN, 256, 0, stream>>>(deg, bsum);
    k_scanB<<<1, 512, 0, stream>>>(bsum);
    k_scanC<<<NB_SCAN, 256, 0, stream>>>(deg, bsum, row_off, cursor, dinv);
    k_fill<<<(N_EDGES + 255) / 256, 256, 0, stream>>>(erow, ecol, cursor, csr);

    int gB = (N_NODES + 127) / 128;
    // embed: h0 = relu(x@We+be) -> Abuf
    gemm_rows<64, 128, true, true, false><<<gB, 256, 0, stream>>>(x, N_NODES, wbuf + OW_We, 128, wbuf + OW_be, Abuf, 128, nullptr, dtflag, nullptr);
    // xw1_scaled = (h0@Wc1) * dinv[row] -> Bbuf
    gemm_rows<128, 128, false, false, true><<<gB, 256, 0, stream>>>(Abuf, N_NODES, wbuf + OW_Wc1, 128, nullptr, Bbuf, 128, dinv, nullptr, nullptr);
    conv_kernel<<<N_NODES / 4, 256, 0, stream>>>(Bbuf, csr, row_off, dinv, wbuf + OW_bc1, Abuf);
    // xw2_scaled = (h1@Wc2) * dinv[row] -> Bbuf
    gemm_rows<128, 128, false, false, true><<<gB, 256, 0, stream>>>(Abuf, N_NODES, wbuf + OW_Wc2, 128, nullptr, Bbuf, 128, dinv, nullptr, nullptr);
    conv_kernel<<<N_NODES / 4, 256, 0, stream>>>(Bbuf, csr, row_off, dinv, wbuf + OW_bc2, Abuf);
    // node head: z = relu(h2@Wn1+bn1) -> Bbuf (pitch 64); logits -> d_out
    gemm_rows<128, 64, true, true, false><<<gB, 256, 0, stream>>>(Abuf, N_NODES, wbuf + OW_Wn1, 64, wbuf + OW_bn1, Bbuf, 64, nullptr, nullptr, nullptr);
    gemm_rows<64, 16, false, true, false><<<gB, 256, 0, stream>>>(Bbuf, N_NODES, wbuf + OW_Wn2, 12, wbuf + OW_bn2, d_out, 12, nullptr, nullptr, dtflag);
    // edge head precompute (dual): P -> Bbuf, Q -> Abuf (in-place safe)
    gemm_pq<<<gB, 256, 0, stream>>>(Abuf, N_NODES, wbuf + OW_We1, wbuf + OW_We1 + 128 * 128, Bbuf, Abuf);
    // fused edge head
    edge_head<<<N_EDGES / 64, 256, 0, stream>>>(ea, erow, ecol, Bbuf, Abuf, wbuf, d_out, dtflag);
}

// Round 5
// 592.920 us; speedup vs baseline: 1.1825x; 1.1155x over previous
//
#include <hip/hip_runtime.h>

#define N_NODES 100000
#define N_EDGES 1000000
#define NB_SCAN 391  /* ceil(N/256) */
#define EDGE_OUT_BASE 1200000  /* N_NODES*12 elements */

typedef __attribute__((ext_vector_type(8))) short short8;
typedef __attribute__((ext_vector_type(4))) unsigned short us4;
typedef __attribute__((ext_vector_type(4))) float f32x4;

__device__ __forceinline__ float bf2f(unsigned short u) {
    unsigned int x = ((unsigned int)u) << 16;
    return __builtin_bit_cast(float, x);
}
__device__ __forceinline__ float lo_bf(unsigned int u) {
    return __builtin_bit_cast(float, u << 16);
}
__device__ __forceinline__ float hi_bf(unsigned int u) {
    return __builtin_bit_cast(float, u & 0xffff0000u);
}
__device__ __forceinline__ unsigned short f2bf(float f) {
    unsigned int x = __builtin_bit_cast(unsigned int, f);
    return (unsigned short)((x + 0x7fffu + ((x >> 16) & 1u)) >> 16);
}

// ---------------- dtype detection ----------------
__global__ __launch_bounds__(256) void k_detect(const unsigned short* __restrict__ xr,
                                                int* __restrict__ flag) {
    __shared__ int s[256];
    int t = threadIdx.x;
    int cnt = 0;
    for (int i = t; i < 8192; i += 256) {
        int e = (xr[i] >> 7) & 0xFF;
        if (e >= 148) cnt++;
    }
    s[t] = cnt;
    __syncthreads();
    for (int off = 128; off > 0; off >>= 1) {
        if (t < off) s[t] += s[t + off];
        __syncthreads();
    }
    if (t == 0) *flag = (s[0] > 100) ? 1 : 0;
}

// ---------------- weight canonicalization (any dtype -> bf16) ----------------
struct WPack { const void* p[14]; };
#define W_TOTAL 87888
__global__ __launch_bounds__(256) void k_convw(WPack wp, const int* __restrict__ flag,
                                               unsigned short* __restrict__ dst) {
    const int starts[15] = {0, 8192, 8320, 24704, 24832, 41216, 41344, 49536,
                            49600, 50368, 50380, 87244, 87372, 87884, 87888};
    bool f32 = (*flag != 0);
    int i = blockIdx.x * 256 + threadIdx.x;
    if (i >= W_TOTAL) return;
    int s = 0;
#pragma unroll
    for (int k = 1; k < 14; k++) s += (i >= starts[k]) ? 1 : 0;
    int j = i - starts[s];
    dst[i] = f32 ? f2bf(((const float*)wp.p[s])[j]) : ((const unsigned short*)wp.p[s])[j];
}
#define OW_We 0
#define OW_be 8192
#define OW_Wc1 8320
#define OW_bc1 24704
#define OW_Wc2 24832
#define OW_bc2 41216
#define OW_Wn1 41344
#define OW_bn1 49536
#define OW_Wn2 49600
#define OW_bn2 50368
#define OW_We1 50380
#define OW_be1 87244
#define OW_We2 87372
#define OW_be2 87884

// ---------------- graph build ----------------
__global__ __launch_bounds__(256) void k_hist(const int* __restrict__ ecol, int* __restrict__ deg) {
    int e = blockIdx.x * 256 + threadIdx.x;
    if (e < N_EDGES) atomicAdd(&deg[ecol[e]], 1);
}

__global__ __launch_bounds__(256) void k_scanA(const int* __restrict__ deg, int* __restrict__ bsum) {
    __shared__ int s[256];
    int i = blockIdx.x * 256 + threadIdx.x;
    s[threadIdx.x] = (i < N_NODES) ? deg[i] : 0;
    __syncthreads();
    for (int off = 128; off > 0; off >>= 1) {
        if (threadIdx.x < off) s[threadIdx.x] += s[threadIdx.x + off];
        __syncthreads();
    }
    if (threadIdx.x == 0) bsum[blockIdx.x] = s[0];
}

__global__ __launch_bounds__(512) void k_scanB(int* __restrict__ bsum) {
    __shared__ int s[512];
    int t = threadIdx.x;
    int v = (t < NB_SCAN) ? bsum[t] : 0;
    s[t] = v;
    __syncthreads();
    for (int off = 1; off < 512; off <<= 1) {
        int x = (t >= off) ? s[t - off] : 0;
        __syncthreads();
        s[t] += x;
        __syncthreads();
    }
    if (t < NB_SCAN) bsum[t] = s[t] - v;  // exclusive
}

__global__ __launch_bounds__(256) void k_scanC(const int* __restrict__ deg, const int* __restrict__ bsum,
                                               int* __restrict__ row_off, int* __restrict__ cursor,
                                               float* __restrict__ dinv) {
    __shared__ int s[256];
    int i = blockIdx.x * 256 + threadIdx.x;
    int t = threadIdx.x;
    int v = (i < N_NODES) ? deg[i] : 0;
    s[t] = v;
    __syncthreads();
    for (int off = 1; off < 256; off <<= 1) {
        int x = (t >= off) ? s[t - off] : 0;
        __syncthreads();
        s[t] += x;
        __syncthreads();
    }
    int excl = s[t] - v + bsum[blockIdx.x];
    if (i < N_NODES) {
        row_off[i] = excl;
        cursor[i] = excl;
        dinv[i] = rsqrtf((float)(v + 1));  // +1 self-loop
    }
    if (i == N_NODES - 1) row_off[N_NODES] = excl + v;
}

__global__ __launch_bounds__(256) void k_fill(const int* __restrict__ erow, const int* __restrict__ ecol,
                                              int* __restrict__ cursor, int* __restrict__ csr) {
    int e = blockIdx.x * 256 + threadIdx.x;
    if (e < N_EDGES) {
        int pos = atomicAdd(&cursor[ecol[e]], 1);
        csr[pos] = erow[e];
    }
}

// ---------------- rows GEMM: Out[M,o_real] = act(A[M,K] @ W[K,o_real] + bias) [* rowscale] ----------------
template <int K, int O, bool RELU, bool BIAS, bool SCALE>
__global__ __launch_bounds__(256) void gemm_rows(const void* __restrict__ A, int M,
                                                 const unsigned short* __restrict__ W, int o_real,
                                                 const unsigned short* __restrict__ bias,
                                                 void* __restrict__ Out, int out_pitch,
                                                 const float* __restrict__ rowscale,
                                                 const int* aflag, const int* oflag) {
    constexpr int KP = K + 8;
    constexpr int KS = K / 32;
    constexpr int OT = O / 16;
    __shared__ short wt[O * KP];
    __shared__ float bias_s[O];
    int tid = threadIdx.x;
    for (int idx = tid; idx < K * O; idx += 256) {
        int k = idx / O, o = idx % O;
        short w = 0;
        if (o < o_real) w = (short)W[(size_t)k * o_real + o];
        wt[o * KP + k] = w;
    }
    if (BIAS) {
        for (int o = tid; o < O; o += 256) bias_s[o] = (o < o_real) ? bf2f(bias[o]) : 0.f;
    }
    __syncthreads();

    bool af32 = aflag && (*aflag != 0);
    bool of32 = oflag && (*oflag != 0);

    int wid = tid >> 6, lane = tid & 63;
    int rbase = (blockIdx.x * 4 + wid) * 32;
    if (rbase >= M) return;
    int lq = lane >> 4, lr = lane & 15;

    short8 a[2][KS];
#pragma unroll
    for (int rg = 0; rg < 2; rg++) {
        int row = rbase + rg * 16 + lr;
        if (row >= M) row = M - 1;
        if (af32) {
            const float* ap = (const float*)A + (size_t)row * K + lq * 8;
#pragma unroll
            for (int ks = 0; ks < KS; ks++) {
                f32x4 u0 = *(const f32x4*)(ap + ks * 32);
                f32x4 u1 = *(const f32x4*)(ap + ks * 32 + 4);
                short8 v;
                v[0] = (short)f2bf(u0[0]); v[1] = (short)f2bf(u0[1]);
                v[2] = (short)f2bf(u0[2]); v[3] = (short)f2bf(u0[3]);
                v[4] = (short)f2bf(u1[0]); v[5] = (short)f2bf(u1[1]);
                v[6] = (short)f2bf(u1[2]); v[7] = (short)f2bf(u1[3]);
                a[rg][ks] = v;
            }
        } else {
            const unsigned short* ap = (const unsigned short*)A + (size_t)row * K + lq * 8;
#pragma unroll
            for (int ks = 0; ks < KS; ks++) a[rg][ks] = *(const short8*)(ap + ks * 32);
        }
    }

    f32x4 acc[2][OT];
#pragma unroll
    for (int rg = 0; rg < 2; rg++)
#pragma unroll
        for (int j = 0; j < OT; j++) {
            acc[rg][j][0] = 0.f; acc[rg][j][1] = 0.f; acc[rg][j][2] = 0.f; acc[rg][j][3] = 0.f;
        }

#pragma unroll
    for (int j = 0; j < OT; j++) {
        short8 b[KS];
#pragma unroll
        for (int ks = 0; ks < KS; ks++)
            b[ks] = *(const short8*)(&wt[(lr + 16 * j) * KP + ks * 32 + lq * 8]);
#pragma unroll
        for (int rg = 0; rg < 2; rg++)
#pragma unroll
            for (int ks = 0; ks < KS; ks++)
                acc[rg][j] = __builtin_amdgcn_mfma_f32_16x16x32_bf16(a[rg][ks], b[ks], acc[rg][j], 0, 0, 0);
    }

    // D layout: col = lane&15, row = (lane>>4)*4 + reg
#pragma unroll
    for (int rg = 0; rg < 2; rg++)
#pragma unroll
        for (int j = 0; j < OT; j++)
#pragma unroll
            for (int r = 0; r < 4; r++) {
                int row = rbase + rg * 16 + lq * 4 + r;
                int col = lr + 16 * j;
                if (row < M && col < o_real) {
                    float v = acc[rg][j][r];
                    if (BIAS) v += bias_s[col];
                    if (RELU) v = fmaxf(v, 0.f);
                    if (SCALE) v *= rowscale[row];
                    size_t oi = (size_t)row * out_pitch + col;
                    if (of32) ((float*)Out)[oi] = v;
                    else ((unsigned short*)Out)[oi] = f2bf(v);
                }
            }
}

// ---------------- dual GEMM for edge-head P/Q — STATIC two-phase (no runtime-indexed arrays) ----------------
// P = A @ W1 -> Pout ; Q = A @ W2 -> Qout (Qout may alias A: A-frags read before any store)
__global__ __launch_bounds__(256) void gemm_pq(const unsigned short* __restrict__ A, int M,
                                               const unsigned short* __restrict__ W1,
                                               const unsigned short* __restrict__ W2,
                                               unsigned short* __restrict__ Pout,
                                               unsigned short* __restrict__ Qout) {
    __shared__ short wt[128 * 136];
    int tid = threadIdx.x;
    int wid = tid >> 6, lane = tid & 63;
    int rbase = (blockIdx.x * 4 + wid) * 32;
    int lq = lane >> 4, lr = lane & 15;

    // A fragments (loaded once, before ANY store)
    short8 a[2][4];
#pragma unroll
    for (int rg = 0; rg < 2; rg++) {
        int row = rbase + rg * 16 + lr;
        if (row >= M) row = M - 1;
        const unsigned short* ap = A + (size_t)row * 128 + lq * 8;
#pragma unroll
        for (int ks = 0; ks < 4; ks++) a[rg][ks] = *(const short8*)(ap + ks * 32);
    }

    // ---- phase P ----
    for (int idx = tid; idx < 128 * 128; idx += 256) {
        int k = idx >> 7, o = idx & 127;
        wt[o * 136 + k] = (short)W1[idx];
    }
    __syncthreads();
    {
        f32x4 acc[2][8];
#pragma unroll
        for (int rg = 0; rg < 2; rg++)
#pragma unroll
            for (int j = 0; j < 8; j++) {
                acc[rg][j][0] = 0.f; acc[rg][j][1] = 0.f; acc[rg][j][2] = 0.f; acc[rg][j][3] = 0.f;
            }
#pragma unroll
        for (int j = 0; j < 8; j++) {
            short8 b[4];
#pragma unroll
            for (int ks = 0; ks < 4; ks++)
                b[ks] = *(const short8*)(&wt[(lr + 16 * j) * 136 + ks * 32 + lq * 8]);
#pragma unroll
            for (int rg = 0; rg < 2; rg++)
#pragma unroll
                for (int ks = 0; ks < 4; ks++)
                    acc[rg][j] = __builtin_amdgcn_mfma_f32_16x16x32_bf16(a[rg][ks], b[ks], acc[rg][j], 0, 0, 0);
        }
#pragma unroll
        for (int rg = 0; rg < 2; rg++)
#pragma unroll
            for (int j = 0; j < 8; j++)
#pragma unroll
                for (int r = 0; r < 4; r++) {
                    int row = rbase + rg * 16 + lq * 4 + r;
                    if (row < M) Pout[(size_t)row * 128 + lr + 16 * j] = f2bf(acc[rg][j][r]);
                }
    }
    __syncthreads();  // all waves done reading wt before restage

    // ---- phase Q ----
    for (int idx = tid; idx < 128 * 128; idx += 256) {
        int k = idx >> 7, o = idx & 127;
        wt[o * 136 + k] = (short)W2[idx];
    }
    __syncthreads();
    {
        f32x4 acc[2][8];
#pragma unroll
        for (int rg = 0; rg < 2; rg++)
#pragma unroll
            for (int j = 0; j < 8; j++) {
                acc[rg][j][0] = 0.f; acc[rg][j][1] = 0.f; acc[rg][j][2] = 0.f; acc[rg][j][3] = 0.f;
            }
#pragma unroll
        for (int j = 0; j < 8; j++) {
            short8 b[4];
#pragma unroll
            for (int ks = 0; ks < 4; ks++)
                b[ks] = *(const short8*)(&wt[(lr + 16 * j) * 136 + ks * 32 + lq * 8]);
#pragma unroll
            for (int rg = 0; rg < 2; rg++)
#pragma unroll
                for (int ks = 0; ks < 4; ks++)
                    acc[rg][j] = __builtin_amdgcn_mfma_f32_16x16x32_bf16(a[rg][ks], b[ks], acc[rg][j], 0, 0, 0);
        }
#pragma unroll
        for (int rg = 0; rg < 2; rg++)
#pragma unroll
            for (int j = 0; j < 8; j++)
#pragma unroll
                for (int r = 0; r < 4; r++) {
                    int row = rbase + rg * 16 + lq * 4 + r;
                    if (row < M) Qout[(size_t)row * 128 + lr + 16 * j] = f2bf(acc[rg][j][r]);
                }
    }
}

// ---------------- GCN conv: prescaled input, unroll-4 gather-sum ----------------
__global__ __launch_bounds__(256) void conv_kernel(const unsigned short* __restrict__ xw_s,
                                                   const int* __restrict__ csr_src,
                                                   const int* __restrict__ row_off,
                                                   const float* __restrict__ dinv,
                                                   const unsigned short* __restrict__ bias,
                                                   unsigned short* __restrict__ out) {
    int wid = threadIdx.x >> 6, lane = threadIdx.x & 63;
    int t = blockIdx.x * 4 + wid;
    int beg = row_off[t], end = row_off[t + 1];
    float dt = dinv[t];
    unsigned int v = *(const unsigned int*)(xw_s + (size_t)t * 128 + lane * 2);
    unsigned int bv = *(const unsigned int*)(bias + lane * 2);
    float a0 = lo_bf(v), a1 = hi_bf(v);
    int i = beg;
    for (; i + 4 <= end; i += 4) {
        int s0 = csr_src[i], s1 = csr_src[i + 1], s2 = csr_src[i + 2], s3 = csr_src[i + 3];
        unsigned int u0 = *(const unsigned int*)(xw_s + (size_t)s0 * 128 + lane * 2);
        unsigned int u1 = *(const unsigned int*)(xw_s + (size_t)s1 * 128 + lane * 2);
        unsigned int u2 = *(const unsigned int*)(xw_s + (size_t)s2 * 128 + lane * 2);
        unsigned int u3 = *(const unsigned int*)(xw_s + (size_t)s3 * 128 + lane * 2);
        a0 += lo_bf(u0) + lo_bf(u1) + lo_bf(u2) + lo_bf(u3);
        a1 += hi_bf(u0) + hi_bf(u1) + hi_bf(u2) + hi_bf(u3);
    }
    for (; i < end; i++) {
        int s = csr_src[i];
        unsigned int u = *(const unsigned int*)(xw_s + (size_t)s * 128 + lane * 2);
        a0 += lo_bf(u);
        a1 += hi_bf(u);
    }
    a0 = fmaxf(fmaf(a0, dt, lo_bf(bv)), 0.f);
    a1 = fmaxf(fmaf(a1, dt, hi_bf(bv)), 0.f);
    unsigned int o = (unsigned int)f2bf(a0) | ((unsigned int)f2bf(a1) << 16);
    *(unsigned int*)(out + (size_t)t * 128 + lane * 2) = o;
}

// ---------------- fused edge head: swapped-MFMA, lane-local epilogue, no T tile ----------------
// acc = Wc3^T(tile j) . ea^T  ->  lane (lq,lr) holds R[ch=16j+4lq+r][edge=lr] in registers.
__global__ __launch_bounds__(256) void edge_head(const void* __restrict__ ea,
                                                 const int* __restrict__ erow, const int* __restrict__ ecol,
                                                 const unsigned short* __restrict__ P,
                                                 const unsigned short* __restrict__ Q,
                                                 const unsigned short* __restrict__ wbuf,
                                                 void* __restrict__ out, const int* dtflag) {
    __shared__ short wct[128 * 40];  // Wc3^T [ch][k], pitch 40
    __shared__ float w2s[128 * 4];   // W2 row-major [ch][o]
    __shared__ float b1s[128];
    int tid = threadIdx.x;
    const unsigned short* Wc3 = wbuf + OW_We1 + 256 * 128;
    for (int idx = tid; idx < 32 * 128; idx += 256) {
        int k = idx >> 7, o = idx & 127;
        wct[o * 40 + k] = (short)Wc3[idx];
    }
    for (int idx = tid; idx < 512; idx += 256) w2s[idx] = bf2f(wbuf[OW_We2 + idx]);
    if (tid < 128) b1s[tid] = bf2f(wbuf[OW_be1 + tid]);
    __syncthreads();

    bool f32io = (*dtflag != 0);
    int wid = tid >> 6, lane = tid & 63;
    int e0 = (blockIdx.x * 4 + wid) * 16;
    int lq = lane >> 4, lr = lane & 15;

    // B-operand: ea^T columns = ea rows (edge e0+lr), k = lq*8..+7
    short8 efrag;
    if (f32io) {
        const float* eap = (const float*)ea + (size_t)(e0 + lr) * 32 + lq * 8;
        f32x4 u0 = *(const f32x4*)eap;
        f32x4 u1 = *(const f32x4*)(eap + 4);
        efrag[0] = (short)f2bf(u0[0]); efrag[1] = (short)f2bf(u0[1]);
        efrag[2] = (short)f2bf(u0[2]); efrag[3] = (short)f2bf(u0[3]);
        efrag[4] = (short)f2bf(u1[0]); efrag[5] = (short)f2bf(u1[1]);
        efrag[6] = (short)f2bf(u1[2]); efrag[7] = (short)f2bf(u1[3]);
    } else {
        efrag = *(const short8*)((const unsigned short*)ea + (size_t)(e0 + lr) * 32 + lq * 8);
    }

    f32x4 zero; zero[0] = 0.f; zero[1] = 0.f; zero[2] = 0.f; zero[3] = 0.f;
    f32x4 acc[8];
#pragma unroll
    for (int j = 0; j < 8; j++) {
        // A-operand: Wc3^T rows 16j+lr, k = lq*8..+7
        short8 wfrag = *(const short8*)(&wct[(16 * j + lr) * 40 + lq * 8]);
        acc[j] = __builtin_amdgcn_mfma_f32_16x16x32_bf16(wfrag, efrag, zero, 0, 0, 0);
    }

    // epilogue: lane (lq,lr) owns edge ge=e0+lr, channels {16j+4lq+r}
    int ge = e0 + lr;
    int rn = erow[ge], cn = ecol[ge];
    const unsigned short* Pp = P + (size_t)rn * 128 + lq * 4;
    const unsigned short* Qp = Q + (size_t)cn * 128 + lq * 4;
    f32x4 ov; ov[0] = 0.f; ov[1] = 0.f; ov[2] = 0.f; ov[3] = 0.f;
#pragma unroll
    for (int j = 0; j < 8; j++) {
        int chb = 16 * j + 4 * lq;
        us4 pv = *(const us4*)(Pp + 16 * j);  // 8B gather chunk
        us4 qv = *(const us4*)(Qp + 16 * j);
        f32x4 b1v = *(const f32x4*)(&b1s[chb]);
#pragma unroll
        for (int r = 0; r < 4; r++) {
            float t = acc[j][r] + bf2f(pv[r]) + bf2f(qv[r]) + b1v[r];
            t = fmaxf(t, 0.f);
            f32x4 w2v = *(const f32x4*)(&w2s[(chb + r) * 4]);
            ov[0] = fmaf(t, w2v[0], ov[0]);
            ov[1] = fmaf(t, w2v[1], ov[1]);
            ov[2] = fmaf(t, w2v[2], ov[2]);
            ov[3] = fmaf(t, w2v[3], ov[3]);
        }
    }
    // reduce across lq (lanes lane^16, lane^32)
#pragma unroll
    for (int c = 0; c < 4; c++) {
        ov[c] += __shfl_xor(ov[c], 16);
        ov[c] += __shfl_xor(ov[c], 32);
    }
    if (lq == 0) {
        size_t oi = (size_t)EDGE_OUT_BASE + (size_t)ge * 4;
        if (f32io) {
            f32x4 res;
#pragma unroll
            for (int c = 0; c < 4; c++) res[c] = ov[c] + bf2f(wbuf[OW_be2 + c]);
            *(f32x4*)((float*)out + oi) = res;
        } else {
            us4 res;
#pragma unroll
            for (int c = 0; c < 4; c++) res[c] = f2bf(ov[c] + bf2f(wbuf[OW_be2 + c]));
            *(us4*)((unsigned short*)out + oi) = res;
        }
    }
}

// ---------------- launcher ----------------
extern "C" void kernel_launch(void* const* d_in, const int* in_sizes, int n_in,
                              void* d_out, int out_size, void* d_ws, size_t ws_size,
                              hipStream_t stream) {
    const void* x = d_in[0];
    const int* ei = (const int*)d_in[1];
    const void* ea = d_in[2];
    const int* erow = ei;
    const int* ecol = ei + N_EDGES;

    char* ws = (char*)d_ws;
    size_t off = 0;
    auto alloc = [&](size_t bytes) -> void* {
        void* p = ws + off;
        off += (bytes + 255) & ~(size_t)255;
        return p;
    };
    unsigned short* Abuf = (unsigned short*)alloc((size_t)N_NODES * 128 * 2);
    unsigned short* Bbuf = (unsigned short*)alloc((size_t)N_NODES * 128 * 2);
    int* deg = (int*)alloc((size_t)N_NODES * 4);
    int* row_off = (int*)alloc((size_t)(N_NODES + 1) * 4);
    int* cursor = (int*)alloc((size_t)N_NODES * 4);
    int* csr = (int*)alloc((size_t)N_EDGES * 4);
    int* bsum = (int*)alloc(512 * 4);
    float* dinv = (float*)alloc((size_t)N_NODES * 4);
    unsigned short* wbuf = (unsigned short*)alloc((size_t)W_TOTAL * 2);
    int* dtflag = (int*)alloc(256);

    // 1. dtype detection (device-side)
    k_detect<<<1, 256, 0, stream>>>((const unsigned short*)x, dtflag);

    // 2. canonicalize weights to bf16
    WPack wp;
    for (int i = 0; i < 14; i++) wp.p[i] = d_in[3 + i];
    k_convw<<<(W_TOTAL + 255) / 256, 256, 0, stream>>>(wp, dtflag, wbuf);

    // 3. graph build
    (void)hipMemsetAsync(deg, 0, (size_t)N_NODES * 4, stream);
    k_hist<<<(N_EDGES + 255) / 256, 256, 0, stream>>>(ecol, deg);
    k_scanA<<<NB_SCAN, 256, 0, stream>>>(deg, bsum);
    k_scanB<<<1, 512, 0, stream>>>(bsum);
    k_scanC<<<NB_SCAN, 256, 0, stream>>>(deg, bsum, row_off, cursor, dinv);
    k_fill<<<(N_EDGES + 255) / 256, 256, 0, stream>>>(erow, ecol, cursor, csr);

    int gB = (N_NODES + 127) / 128;
    // embed: h0 = relu(x@We+be) -> Abuf
    gemm_rows<64, 128, true, true, false><<<gB, 256, 0, stream>>>(x, N_NODES, wbuf + OW_We, 128, wbuf + OW_be, Abuf, 128, nullptr, dtflag, nullptr);
    // xw1_scaled = (h0@Wc1) * dinv[row] -> Bbuf
    gemm_rows<128, 128, false, false, true><<<gB, 256, 0, stream>>>(Abuf, N_NODES, wbuf + OW_Wc1, 128, nullptr, Bbuf, 128, dinv, nullptr, nullptr);
    conv_kernel<<<N_NODES / 4, 256, 0, stream>>>(Bbuf, csr, row_off, dinv, wbuf + OW_bc1, Abuf);
    // xw2_scaled = (h1@Wc2) * dinv[row] -> Bbuf
    gemm_rows<128, 128, false, false, true><<<gB, 256, 0, stream>>>(Abuf, N_NODES, wbuf + OW_Wc2, 128, nullptr, Bbuf, 128, dinv, nullptr, nullptr);
    conv_kernel<<<N_NODES / 4, 256, 0, stream>>>(Bbuf, csr, row_off, dinv, wbuf + OW_bc2, Abuf);
    // node head: z = relu(h2@Wn1+bn1) -> Bbuf (pitch 64); logits -> d_out
    gemm_rows<128, 64, true, true, false><<<gB, 256, 0, stream>>>(Abuf, N_NODES, wbuf + OW_Wn1, 64, wbuf + OW_bn1, Bbuf, 64, nullptr, nullptr, nullptr);
    gemm_rows<64, 16, false, true, false><<<gB, 256, 0, stream>>>(Bbuf, N_NODES, wbuf + OW_Wn2, 12, wbuf + OW_bn2, d_out, 12, nullptr, nullptr, dtflag);
    // edge head precompute (dual, static): P -> Bbuf, Q -> Abuf (in-place safe)
    gemm_pq<<<gB, 256, 0, stream>>>(Abuf, N_NODES, wbuf + OW_We1, wbuf + OW_We1 + 128 * 128, Bbuf, Abuf);
    // fused edge head
    edge_head<<<N_EDGES / 64, 256, 0, stream>>>(ea, erow, ecol, Bbuf, Abuf, wbuf, d_out, dtflag);
}

// Round 6
// 559.529 us; speedup vs baseline: 1.2531x; 1.0597x over previous
//
#include <hip/hip_runtime.h>

#define N_NODES 100000
#define N_EDGES 1000000
#define NB_SCAN 391  /* ceil(N/256) */
#define EDGE_OUT_BASE 1200000  /* N_NODES*12 elements */

typedef __attribute__((ext_vector_type(8))) short short8;
typedef __attribute__((ext_vector_type(4))) unsigned short us4;
typedef __attribute__((ext_vector_type(4))) float f32x4;

__device__ __forceinline__ float bf2f(unsigned short u) {
    unsigned int x = ((unsigned int)u) << 16;
    return __builtin_bit_cast(float, x);
}
__device__ __forceinline__ float lo_bf(unsigned int u) {
    return __builtin_bit_cast(float, u << 16);
}
__device__ __forceinline__ float hi_bf(unsigned int u) {
    return __builtin_bit_cast(float, u & 0xffff0000u);
}
__device__ __forceinline__ unsigned short f2bf(float f) {
    unsigned int x = __builtin_bit_cast(unsigned int, f);
    return (unsigned short)((x + 0x7fffu + ((x >> 16) & 1u)) >> 16);
}

// ---------------- dtype detection ----------------
__global__ __launch_bounds__(256) void k_detect(const unsigned short* __restrict__ xr,
                                                int* __restrict__ flag) {
    __shared__ int s[256];
    int t = threadIdx.x;
    int cnt = 0;
    for (int i = t; i < 8192; i += 256) {
        int e = (xr[i] >> 7) & 0xFF;
        if (e >= 148) cnt++;
    }
    s[t] = cnt;
    __syncthreads();
    for (int off = 128; off > 0; off >>= 1) {
        if (t < off) s[t] += s[t + off];
        __syncthreads();
    }
    if (t == 0) *flag = (s[0] > 100) ? 1 : 0;
}

// ---------------- weight canonicalization (any dtype -> bf16) ----------------
struct WPack { const void* p[14]; };
#define W_TOTAL 87888
__global__ __launch_bounds__(256) void k_convw(WPack wp, const int* __restrict__ flag,
                                               unsigned short* __restrict__ dst) {
    const int starts[15] = {0, 8192, 8320, 24704, 24832, 41216, 41344, 49536,
                            49600, 50368, 50380, 87244, 87372, 87884, 87888};
    bool f32 = (*flag != 0);
    int i = blockIdx.x * 256 + threadIdx.x;
    if (i >= W_TOTAL) return;
    int s = 0;
#pragma unroll
    for (int k = 1; k < 14; k++) s += (i >= starts[k]) ? 1 : 0;
    int j = i - starts[s];
    dst[i] = f32 ? f2bf(((const float*)wp.p[s])[j]) : ((const unsigned short*)wp.p[s])[j];
}
#define OW_We 0
#define OW_be 8192
#define OW_Wc1 8320
#define OW_bc1 24704
#define OW_Wc2 24832
#define OW_bc2 41216
#define OW_Wn1 41344
#define OW_bn1 49536
#define OW_Wn2 49600
#define OW_bn2 50368
#define OW_We1 50380
#define OW_be1 87244
#define OW_We2 87372
#define OW_be2 87884

// ---------------- graph build ----------------
__global__ __launch_bounds__(256) void k_hist(const int* __restrict__ ecol, int* __restrict__ deg) {
    int e = blockIdx.x * 256 + threadIdx.x;
    if (e < N_EDGES) atomicAdd(&deg[ecol[e]], 1);
}

__global__ __launch_bounds__(256) void k_scanA(const int* __restrict__ deg, int* __restrict__ bsum) {
    __shared__ int s[256];
    int i = blockIdx.x * 256 + threadIdx.x;
    s[threadIdx.x] = (i < N_NODES) ? deg[i] : 0;
    __syncthreads();
    for (int off = 128; off > 0; off >>= 1) {
        if (threadIdx.x < off) s[threadIdx.x] += s[threadIdx.x + off];
        __syncthreads();
    }
    if (threadIdx.x == 0) bsum[blockIdx.x] = s[0];
}

__global__ __launch_bounds__(512) void k_scanB(int* __restrict__ bsum) {
    __shared__ int s[512];
    int t = threadIdx.x;
    int v = (t < NB_SCAN) ? bsum[t] : 0;
    s[t] = v;
    __syncthreads();
    for (int off = 1; off < 512; off <<= 1) {
        int x = (t >= off) ? s[t - off] : 0;
        __syncthreads();
        s[t] += x;
        __syncthreads();
    }
    if (t < NB_SCAN) bsum[t] = s[t] - v;  // exclusive
}

__global__ __launch_bounds__(256) void k_scanC(const int* __restrict__ deg, const int* __restrict__ bsum,
                                               int* __restrict__ row_off, int* __restrict__ cursor,
                                               float* __restrict__ dinv) {
    __shared__ int s[256];
    int i = blockIdx.x * 256 + threadIdx.x;
    int t = threadIdx.x;
    int v = (i < N_NODES) ? deg[i] : 0;
    s[t] = v;
    __syncthreads();
    for (int off = 1; off < 256; off <<= 1) {
        int x = (t >= off) ? s[t - off] : 0;
        __syncthreads();
        s[t] += x;
        __syncthreads();
    }
    int excl = s[t] - v + bsum[blockIdx.x];
    if (i < N_NODES) {
        row_off[i] = excl;
        cursor[i] = excl;
        dinv[i] = rsqrtf((float)(v + 1));  // +1 self-loop
    }
    if (i == N_NODES - 1) row_off[N_NODES] = excl + v;
}

__global__ __launch_bounds__(256) void k_fill(const int* __restrict__ erow, const int* __restrict__ ecol,
                                              int* __restrict__ cursor, int* __restrict__ csr) {
    int e = blockIdx.x * 256 + threadIdx.x;
    if (e < N_EDGES) {
        int pos = atomicAdd(&cursor[ecol[e]], 1);
        csr[pos] = erow[e];
    }
}

// ---------------- rows GEMM: Out[M,o_real] = act(A[M,K] @ W[K,o_real] + bias) [* rowscale] ----------------
template <int K, int O, bool RELU, bool BIAS, bool SCALE>
__global__ __launch_bounds__(256) void gemm_rows(const void* __restrict__ A, int M,
                                                 const unsigned short* __restrict__ W, int o_real,
                                                 const unsigned short* __restrict__ bias,
                                                 void* __restrict__ Out, int out_pitch,
                                                 const float* __restrict__ rowscale,
                                                 const int* aflag, const int* oflag) {
    constexpr int KP = K + 8;
    constexpr int KS = K / 32;
    constexpr int OT = O / 16;
    __shared__ short wt[O * KP];
    __shared__ float bias_s[O];
    int tid = threadIdx.x;
    for (int idx = tid; idx < K * O; idx += 256) {
        int k = idx / O, o = idx % O;
        short w = 0;
        if (o < o_real) w = (short)W[(size_t)k * o_real + o];
        wt[o * KP + k] = w;
    }
    if (BIAS) {
        for (int o = tid; o < O; o += 256) bias_s[o] = (o < o_real) ? bf2f(bias[o]) : 0.f;
    }
    __syncthreads();

    bool af32 = aflag && (*aflag != 0);
    bool of32 = oflag && (*oflag != 0);

    int wid = tid >> 6, lane = tid & 63;
    int rbase = (blockIdx.x * 4 + wid) * 32;
    if (rbase >= M) return;
    int lq = lane >> 4, lr = lane & 15;

    short8 a[2][KS];
#pragma unroll
    for (int rg = 0; rg < 2; rg++) {
        int row = rbase + rg * 16 + lr;
        if (row >= M) row = M - 1;
        if (af32) {
            const float* ap = (const float*)A + (size_t)row * K + lq * 8;
#pragma unroll
            for (int ks = 0; ks < KS; ks++) {
                f32x4 u0 = *(const f32x4*)(ap + ks * 32);
                f32x4 u1 = *(const f32x4*)(ap + ks * 32 + 4);
                short8 v;
                v[0] = (short)f2bf(u0[0]); v[1] = (short)f2bf(u0[1]);
                v[2] = (short)f2bf(u0[2]); v[3] = (short)f2bf(u0[3]);
                v[4] = (short)f2bf(u1[0]); v[5] = (short)f2bf(u1[1]);
                v[6] = (short)f2bf(u1[2]); v[7] = (short)f2bf(u1[3]);
                a[rg][ks] = v;
            }
        } else {
            const unsigned short* ap = (const unsigned short*)A + (size_t)row * K + lq * 8;
#pragma unroll
            for (int ks = 0; ks < KS; ks++) a[rg][ks] = *(const short8*)(ap + ks * 32);
        }
    }

    f32x4 acc[2][OT];
#pragma unroll
    for (int rg = 0; rg < 2; rg++)
#pragma unroll
        for (int j = 0; j < OT; j++) {
            acc[rg][j][0] = 0.f; acc[rg][j][1] = 0.f; acc[rg][j][2] = 0.f; acc[rg][j][3] = 0.f;
        }

#pragma unroll
    for (int j = 0; j < OT; j++) {
        short8 b[KS];
#pragma unroll
        for (int ks = 0; ks < KS; ks++)
            b[ks] = *(const short8*)(&wt[(lr + 16 * j) * KP + ks * 32 + lq * 8]);
#pragma unroll
        for (int rg = 0; rg < 2; rg++)
#pragma unroll
            for (int ks = 0; ks < KS; ks++)
                acc[rg][j] = __builtin_amdgcn_mfma_f32_16x16x32_bf16(a[rg][ks], b[ks], acc[rg][j], 0, 0, 0);
    }

    // D layout: col = lane&15, row = (lane>>4)*4 + reg
#pragma unroll
    for (int rg = 0; rg < 2; rg++)
#pragma unroll
        for (int j = 0; j < OT; j++)
#pragma unroll
            for (int r = 0; r < 4; r++) {
                int row = rbase + rg * 16 + lq * 4 + r;
                int col = lr + 16 * j;
                if (row < M && col < o_real) {
                    float v = acc[rg][j][r];
                    if (BIAS) v += bias_s[col];
                    if (RELU) v = fmaxf(v, 0.f);
                    if (SCALE) v *= rowscale[row];
                    size_t oi = (size_t)row * out_pitch + col;
                    if (of32) ((float*)Out)[oi] = v;
                    else ((unsigned short*)Out)[oi] = f2bf(v);
                }
            }
}

// ---------------- dual GEMM for edge-head P/Q — PERMUTED channel layout ----------------
// Stores channel (16j + 4lq + r) at position (lq*32 + j*4 + r) so edge_head's lane lq
// reads its 32 owned channels as one contiguous 64B run.
__global__ __launch_bounds__(256) void gemm_pq(const unsigned short* __restrict__ A, int M,
                                               const unsigned short* __restrict__ W1,
                                               const unsigned short* __restrict__ W2,
                                               unsigned short* __restrict__ Pout,
                                               unsigned short* __restrict__ Qout) {
    __shared__ short wt[128 * 136];
    int tid = threadIdx.x;
    int wid = tid >> 6, lane = tid & 63;
    int rbase = (blockIdx.x * 4 + wid) * 32;
    int lq = lane >> 4, lr = lane & 15;

    // A fragments (loaded once, before ANY store)
    short8 a[2][4];
#pragma unroll
    for (int rg = 0; rg < 2; rg++) {
        int row = rbase + rg * 16 + lr;
        if (row >= M) row = M - 1;
        const unsigned short* ap = A + (size_t)row * 128 + lq * 8;
#pragma unroll
        for (int ks = 0; ks < 4; ks++) a[rg][ks] = *(const short8*)(ap + ks * 32);
    }

    // col = lr + 16j -> permuted position = (lr>>2)*32 + j*4 + (lr&3)
    int pc0 = (lr >> 2) * 32 + (lr & 3);

    // ---- phase P ----
    for (int idx = tid; idx < 128 * 128; idx += 256) {
        int k = idx >> 7, o = idx & 127;
        wt[o * 136 + k] = (short)W1[idx];
    }
    __syncthreads();
    {
        f32x4 acc[2][8];
#pragma unroll
        for (int rg = 0; rg < 2; rg++)
#pragma unroll
            for (int j = 0; j < 8; j++) {
                acc[rg][j][0] = 0.f; acc[rg][j][1] = 0.f; acc[rg][j][2] = 0.f; acc[rg][j][3] = 0.f;
            }
#pragma unroll
        for (int j = 0; j < 8; j++) {
            short8 b[4];
#pragma unroll
            for (int ks = 0; ks < 4; ks++)
                b[ks] = *(const short8*)(&wt[(lr + 16 * j) * 136 + ks * 32 + lq * 8]);
#pragma unroll
            for (int rg = 0; rg < 2; rg++)
#pragma unroll
                for (int ks = 0; ks < 4; ks++)
                    acc[rg][j] = __builtin_amdgcn_mfma_f32_16x16x32_bf16(a[rg][ks], b[ks], acc[rg][j], 0, 0, 0);
        }
#pragma unroll
        for (int rg = 0; rg < 2; rg++)
#pragma unroll
            for (int j = 0; j < 8; j++)
#pragma unroll
                for (int r = 0; r < 4; r++) {
                    int row = rbase + rg * 16 + lq * 4 + r;
                    if (row < M) Pout[(size_t)row * 128 + pc0 + j * 4] = f2bf(acc[rg][j][r]);
                }
    }
    __syncthreads();  // all waves done reading wt before restage

    // ---- phase Q ----
    for (int idx = tid; idx < 128 * 128; idx += 256) {
        int k = idx >> 7, o = idx & 127;
        wt[o * 136 + k] = (short)W2[idx];
    }
    __syncthreads();
    {
        f32x4 acc[2][8];
#pragma unroll
        for (int rg = 0; rg < 2; rg++)
#pragma unroll
            for (int j = 0; j < 8; j++) {
                acc[rg][j][0] = 0.f; acc[rg][j][1] = 0.f; acc[rg][j][2] = 0.f; acc[rg][j][3] = 0.f;
            }
#pragma unroll
        for (int j = 0; j < 8; j++) {
            short8 b[4];
#pragma unroll
            for (int ks = 0; ks < 4; ks++)
                b[ks] = *(const short8*)(&wt[(lr + 16 * j) * 136 + ks * 32 + lq * 8]);
#pragma unroll
            for (int rg = 0; rg < 2; rg++)
#pragma unroll
                for (int ks = 0; ks < 4; ks++)
                    acc[rg][j] = __builtin_amdgcn_mfma_f32_16x16x32_bf16(a[rg][ks], b[ks], acc[rg][j], 0, 0, 0);
        }
#pragma unroll
        for (int rg = 0; rg < 2; rg++)
#pragma unroll
            for (int j = 0; j < 8; j++)
#pragma unroll
                for (int r = 0; r < 4; r++) {
                    int row = rbase + rg * 16 + lq * 4 + r;
                    if (row < M) Qout[(size_t)row * 128 + pc0 + j * 4] = f2bf(acc[rg][j][r]);
                }
    }
}

// ---------------- GCN conv: 2 nodes/wave, dual unroll-4 gather streams ----------------
__global__ __launch_bounds__(256) void conv_kernel(const unsigned short* __restrict__ xw_s,
                                                   const int* __restrict__ csr_src,
                                                   const int* __restrict__ row_off,
                                                   const float* __restrict__ dinv,
                                                   const unsigned short* __restrict__ bias,
                                                   unsigned short* __restrict__ out) {
    int wid = threadIdx.x >> 6, lane = threadIdx.x & 63;
    int base = (blockIdx.x * 4 + wid) * 2;  // grid = N/8
    int t0 = base, t1 = base + 1;
    int beg0 = row_off[t0], end0 = row_off[t0 + 1];
    int beg1 = row_off[t1], end1 = row_off[t1 + 1];
    float dt0 = dinv[t0], dt1 = dinv[t1];
    unsigned int v0 = *(const unsigned int*)(xw_s + (size_t)t0 * 128 + lane * 2);
    unsigned int v1 = *(const unsigned int*)(xw_s + (size_t)t1 * 128 + lane * 2);
    unsigned int bv = *(const unsigned int*)(bias + lane * 2);
    float a00 = lo_bf(v0), a01 = hi_bf(v0);
    float a10 = lo_bf(v1), a11 = hi_bf(v1);
    int i0 = beg0, i1 = beg1;
    // dual stream: 8 independent gathers in flight
    while (i0 + 4 <= end0 && i1 + 4 <= end1) {
        int s00 = csr_src[i0], s01 = csr_src[i0 + 1], s02 = csr_src[i0 + 2], s03 = csr_src[i0 + 3];
        int s10 = csr_src[i1], s11 = csr_src[i1 + 1], s12 = csr_src[i1 + 2], s13 = csr_src[i1 + 3];
        unsigned int u00 = *(const unsigned int*)(xw_s + (size_t)s00 * 128 + lane * 2);
        unsigned int u01 = *(const unsigned int*)(xw_s + (size_t)s01 * 128 + lane * 2);
        unsigned int u02 = *(const unsigned int*)(xw_s + (size_t)s02 * 128 + lane * 2);
        unsigned int u03 = *(const unsigned int*)(xw_s + (size_t)s03 * 128 + lane * 2);
        unsigned int u10 = *(const unsigned int*)(xw_s + (size_t)s10 * 128 + lane * 2);
        unsigned int u11 = *(const unsigned int*)(xw_s + (size_t)s11 * 128 + lane * 2);
        unsigned int u12 = *(const unsigned int*)(xw_s + (size_t)s12 * 128 + lane * 2);
        unsigned int u13 = *(const unsigned int*)(xw_s + (size_t)s13 * 128 + lane * 2);
        a00 += lo_bf(u00) + lo_bf(u01) + lo_bf(u02) + lo_bf(u03);
        a01 += hi_bf(u00) + hi_bf(u01) + hi_bf(u02) + hi_bf(u03);
        a10 += lo_bf(u10) + lo_bf(u11) + lo_bf(u12) + lo_bf(u13);
        a11 += hi_bf(u10) + hi_bf(u11) + hi_bf(u12) + hi_bf(u13);
        i0 += 4; i1 += 4;
    }
    for (; i0 + 4 <= end0; i0 += 4) {
        int s0 = csr_src[i0], s1 = csr_src[i0 + 1], s2 = csr_src[i0 + 2], s3 = csr_src[i0 + 3];
        unsigned int u0 = *(const unsigned int*)(xw_s + (size_t)s0 * 128 + lane * 2);
        unsigned int u1 = *(const unsigned int*)(xw_s + (size_t)s1 * 128 + lane * 2);
        unsigned int u2 = *(const unsigned int*)(xw_s + (size_t)s2 * 128 + lane * 2);
        unsigned int u3 = *(const unsigned int*)(xw_s + (size_t)s3 * 128 + lane * 2);
        a00 += lo_bf(u0) + lo_bf(u1) + lo_bf(u2) + lo_bf(u3);
        a01 += hi_bf(u0) + hi_bf(u1) + hi_bf(u2) + hi_bf(u3);
    }
    for (; i1 + 4 <= end1; i1 += 4) {
        int s0 = csr_src[i1], s1 = csr_src[i1 + 1], s2 = csr_src[i1 + 2], s3 = csr_src[i1 + 3];
        unsigned int u0 = *(const unsigned int*)(xw_s + (size_t)s0 * 128 + lane * 2);
        unsigned int u1 = *(const unsigned int*)(xw_s + (size_t)s1 * 128 + lane * 2);
        unsigned int u2 = *(const unsigned int*)(xw_s + (size_t)s2 * 128 + lane * 2);
        unsigned int u3 = *(const unsigned int*)(xw_s + (size_t)s3 * 128 + lane * 2);
        a10 += lo_bf(u0) + lo_bf(u1) + lo_bf(u2) + lo_bf(u3);
        a11 += hi_bf(u0) + hi_bf(u1) + hi_bf(u2) + hi_bf(u3);
    }
    for (; i0 < end0; i0++) {
        int s = csr_src[i0];
        unsigned int u = *(const unsigned int*)(xw_s + (size_t)s * 128 + lane * 2);
        a00 += lo_bf(u); a01 += hi_bf(u);
    }
    for (; i1 < end1; i1++) {
        int s = csr_src[i1];
        unsigned int u = *(const unsigned int*)(xw_s + (size_t)s * 128 + lane * 2);
        a10 += lo_bf(u); a11 += hi_bf(u);
    }
    a00 = fmaxf(fmaf(a00, dt0, lo_bf(bv)), 0.f);
    a01 = fmaxf(fmaf(a01, dt0, hi_bf(bv)), 0.f);
    a10 = fmaxf(fmaf(a10, dt1, lo_bf(bv)), 0.f);
    a11 = fmaxf(fmaf(a11, dt1, hi_bf(bv)), 0.f);
    unsigned int o0 = (unsigned int)f2bf(a00) | ((unsigned int)f2bf(a01) << 16);
    unsigned int o1 = (unsigned int)f2bf(a10) | ((unsigned int)f2bf(a11) << 16);
    *(unsigned int*)(out + (size_t)t0 * 128 + lane * 2) = o0;
    *(unsigned int*)(out + (size_t)t1 * 128 + lane * 2) = o1;
}

// ---------------- fused edge head: swapped-MFMA + permuted P/Q + 2 tiles/wave ----------------
__global__ __launch_bounds__(256) void edge_head(const void* __restrict__ ea,
                                                 const int* __restrict__ erow, const int* __restrict__ ecol,
                                                 const unsigned short* __restrict__ P,
                                                 const unsigned short* __restrict__ Q,
                                                 const unsigned short* __restrict__ wbuf,
                                                 void* __restrict__ out, const int* dtflag) {
    __shared__ short wct[128 * 40];  // Wc3^T [ch][k], pitch 40
    __shared__ float w2s[128 * 4];   // permuted: w2s[p*4+o], p = lq*32+j*4+r
    __shared__ float b1s[128];       // permuted
    int tid = threadIdx.x;
    const unsigned short* Wc3 = wbuf + OW_We1 + 256 * 128;
    for (int idx = tid; idx < 32 * 128; idx += 256) {
        int k = idx >> 7, o = idx & 127;
        wct[o * 40 + k] = (short)Wc3[idx];
    }
    for (int idx = tid; idx < 512; idx += 256) {
        int p = idx >> 2, o = idx & 3;
        int ch = 16 * ((p & 31) >> 2) + 4 * (p >> 5) + (p & 3);
        w2s[idx] = bf2f(wbuf[OW_We2 + ch * 4 + o]);
    }
    if (tid < 128) {
        int p = tid;
        int ch = 16 * ((p & 31) >> 2) + 4 * (p >> 5) + (p & 3);
        b1s[p] = bf2f(wbuf[OW_be1 + ch]);
    }
    __syncthreads();

    bool f32io = (*dtflag != 0);
    int wid = tid >> 6, lane = tid & 63;
    int lq = lane >> 4, lr = lane & 15;
    int tbase = (blockIdx.x * 4 + wid) * 2;
    int e0a = tbase * 16, e0b = e0a + 16;

    int gea = e0a + lr, geb = e0b + lr;
    bool va = gea < N_EDGES, vb = geb < N_EDGES;
    int geca = va ? gea : (N_EDGES - 1);
    int gecb = vb ? geb : (N_EDGES - 1);

    // indices early (independent of MFMA chain)
    int rna = erow[geca], cna = ecol[geca];
    int rnb = erow[gecb], cnb = ecol[gecb];

    auto load_efrag = [&](int ge) -> short8 {
        short8 v;
        if (f32io) {
            const float* eap = (const float*)ea + (size_t)ge * 32 + lq * 8;
            f32x4 u0 = *(const f32x4*)eap;
            f32x4 u1 = *(const f32x4*)(eap + 4);
            v[0] = (short)f2bf(u0[0]); v[1] = (short)f2bf(u0[1]);
            v[2] = (short)f2bf(u0[2]); v[3] = (short)f2bf(u0[3]);
            v[4] = (short)f2bf(u1[0]); v[5] = (short)f2bf(u1[1]);
            v[6] = (short)f2bf(u1[2]); v[7] = (short)f2bf(u1[3]);
        } else {
            v = *(const short8*)((const unsigned short*)ea + (size_t)ge * 32 + lq * 8);
        }
        return v;
    };
    short8 efA = load_efrag(geca);
    short8 efB = load_efrag(gecb);

    f32x4 zero; zero[0] = 0.f; zero[1] = 0.f; zero[2] = 0.f; zero[3] = 0.f;
    f32x4 accA[8], accB[8];
#pragma unroll
    for (int j = 0; j < 8; j++) {
        short8 wfrag = *(const short8*)(&wct[(16 * j + lr) * 40 + lq * 8]);
        accA[j] = __builtin_amdgcn_mfma_f32_16x16x32_bf16(wfrag, efA, zero, 0, 0, 0);
        accB[j] = __builtin_amdgcn_mfma_f32_16x16x32_bf16(wfrag, efB, zero, 0, 0, 0);
    }

    // lane (lq,lr): edge lr of its tile, permuted channels [lq*32, lq*32+32)
    const unsigned short* PpA = P + (size_t)rna * 128 + lq * 32;
    const unsigned short* QpA = Q + (size_t)cna * 128 + lq * 32;
    const unsigned short* PpB = P + (size_t)rnb * 128 + lq * 32;
    const unsigned short* QpB = Q + (size_t)cnb * 128 + lq * 32;
    f32x4 ovA, ovB;
    ovA[0] = 0.f; ovA[1] = 0.f; ovA[2] = 0.f; ovA[3] = 0.f;
    ovB[0] = 0.f; ovB[1] = 0.f; ovB[2] = 0.f; ovB[3] = 0.f;
#pragma unroll
    for (int c = 0; c < 4; c++) {
        short8 pvA = *(const short8*)(PpA + c * 8);  // 16B contiguous
        short8 qvA = *(const short8*)(QpA + c * 8);
        short8 pvB = *(const short8*)(PpB + c * 8);
        short8 qvB = *(const short8*)(QpB + c * 8);
        int pbase = lq * 32 + c * 8;
#pragma unroll
        for (int jj = 0; jj < 2; jj++) {
            int j = 2 * c + jj;
#pragma unroll
            for (int r = 0; r < 4; r++) {
                int idx = jj * 4 + r;
                float b1v = b1s[pbase + idx];
                f32x4 w2v = *(const f32x4*)(&w2s[(pbase + idx) * 4]);
                float tA = accA[j][r] + bf2f((unsigned short)pvA[idx]) + bf2f((unsigned short)qvA[idx]) + b1v;
                tA = fmaxf(tA, 0.f);
                ovA[0] = fmaf(tA, w2v[0], ovA[0]);
                ovA[1] = fmaf(tA, w2v[1], ovA[1]);
                ovA[2] = fmaf(tA, w2v[2], ovA[2]);
                ovA[3] = fmaf(tA, w2v[3], ovA[3]);
                float tB = accB[j][r] + bf2f((unsigned short)pvB[idx]) + bf2f((unsigned short)qvB[idx]) + b1v;
                tB = fmaxf(tB, 0.f);
                ovB[0] = fmaf(tB, w2v[0], ovB[0]);
                ovB[1] = fmaf(tB, w2v[1], ovB[1]);
                ovB[2] = fmaf(tB, w2v[2], ovB[2]);
                ovB[3] = fmaf(tB, w2v[3], ovB[3]);
            }
        }
    }
    // reduce across lq (lane bits 4,5)
#pragma unroll
    for (int c = 0; c < 4; c++) {
        ovA[c] += __shfl_xor(ovA[c], 16);
        ovA[c] += __shfl_xor(ovA[c], 32);
        ovB[c] += __shfl_xor(ovB[c], 16);
        ovB[c] += __shfl_xor(ovB[c], 32);
    }
    if (lq == 0) {
        float be2_0 = bf2f(wbuf[OW_be2 + 0]), be2_1 = bf2f(wbuf[OW_be2 + 1]);
        float be2_2 = bf2f(wbuf[OW_be2 + 2]), be2_3 = bf2f(wbuf[OW_be2 + 3]);
        if (va) {
            size_t oi = (size_t)EDGE_OUT_BASE + (size_t)gea * 4;
            if (f32io) {
                f32x4 res; res[0] = ovA[0] + be2_0; res[1] = ovA[1] + be2_1;
                res[2] = ovA[2] + be2_2; res[3] = ovA[3] + be2_3;
                *(f32x4*)((float*)out + oi) = res;
            } else {
                us4 res; res[0] = f2bf(ovA[0] + be2_0); res[1] = f2bf(ovA[1] + be2_1);
                res[2] = f2bf(ovA[2] + be2_2); res[3] = f2bf(ovA[3] + be2_3);
                *(us4*)((unsigned short*)out + oi) = res;
            }
        }
        if (vb) {
            size_t oi = (size_t)EDGE_OUT_BASE + (size_t)geb * 4;
            if (f32io) {
                f32x4 res; res[0] = ovB[0] + be2_0; res[1] = ovB[1] + be2_1;
                res[2] = ovB[2] + be2_2; res[3] = ovB[3] + be2_3;
                *(f32x4*)((float*)out + oi) = res;
            } else {
                us4 res; res[0] = f2bf(ovB[0] + be2_0); res[1] = f2bf(ovB[1] + be2_1);
                res[2] = f2bf(ovB[2] + be2_2); res[3] = f2bf(ovB[3] + be2_3);
                *(us4*)((unsigned short*)out + oi) = res;
            }
        }
    }
}

// ---------------- launcher ----------------
extern "C" void kernel_launch(void* const* d_in, const int* in_sizes, int n_in,
                              void* d_out, int out_size, void* d_ws, size_t ws_size,
                              hipStream_t stream) {
    const void* x = d_in[0];
    const int* ei = (const int*)d_in[1];
    const void* ea = d_in[2];
    const int* erow = ei;
    const int* ecol = ei + N_EDGES;

    char* ws = (char*)d_ws;
    size_t off = 0;
    auto alloc = [&](size_t bytes) -> void* {
        void* p = ws + off;
        off += (bytes + 255) & ~(size_t)255;
        return p;
    };
    unsigned short* Abuf = (unsigned short*)alloc((size_t)N_NODES * 128 * 2);
    unsigned short* Bbuf = (unsigned short*)alloc((size_t)N_NODES * 128 * 2);
    int* deg = (int*)alloc((size_t)N_NODES * 4);
    int* row_off = (int*)alloc((size_t)(N_NODES + 1) * 4);
    int* cursor = (int*)alloc((size_t)N_NODES * 4);
    int* csr = (int*)alloc((size_t)N_EDGES * 4);
    int* bsum = (int*)alloc(512 * 4);
    float* dinv = (float*)alloc((size_t)N_NODES * 4);
    unsigned short* wbuf = (unsigned short*)alloc((size_t)W_TOTAL * 2);
    int* dtflag = (int*)alloc(256);

    // 1. dtype detection (device-side)
    k_detect<<<1, 256, 0, stream>>>((const unsigned short*)x, dtflag);

    // 2. canonicalize weights to bf16
    WPack wp;
    for (int i = 0; i < 14; i++) wp.p[i] = d_in[3 + i];
    k_convw<<<(W_TOTAL + 255) / 256, 256, 0, stream>>>(wp, dtflag, wbuf);

    // 3. graph build
    (void)hipMemsetAsync(deg, 0, (size_t)N_NODES * 4, stream);
    k_hist<<<(N_EDGES + 255) / 256, 256, 0, stream>>>(ecol, deg);
    k_scanA<<<NB_SCAN, 256, 0, stream>>>(deg, bsum);
    k_scanB<<<1, 512, 0, stream>>>(bsum);
    k_scanC<<<NB_SCAN, 256, 0, stream>>>(deg, bsum, row_off, cursor, dinv);
    k_fill<<<(N_EDGES + 255) / 256, 256, 0, stream>>>(erow, ecol, cursor, csr);

    int gB = (N_NODES + 127) / 128;
    // embed: h0 = relu(x@We+be) -> Abuf
    gemm_rows<64, 128, true, true, false><<<gB, 256, 0, stream>>>(x, N_NODES, wbuf + OW_We, 128, wbuf + OW_be, Abuf, 128, nullptr, dtflag, nullptr);
    // xw1_scaled = (h0@Wc1) * dinv[row] -> Bbuf
    gemm_rows<128, 128, false, false, true><<<gB, 256, 0, stream>>>(Abuf, N_NODES, wbuf + OW_Wc1, 128, nullptr, Bbuf, 128, dinv, nullptr, nullptr);
    conv_kernel<<<N_NODES / 8, 256, 0, stream>>>(Bbuf, csr, row_off, dinv, wbuf + OW_bc1, Abuf);
    // xw2_scaled = (h1@Wc2) * dinv[row] -> Bbuf
    gemm_rows<128, 128, false, false, true><<<gB, 256, 0, stream>>>(Abuf, N_NODES, wbuf + OW_Wc2, 128, nullptr, Bbuf, 128, dinv, nullptr, nullptr);
    conv_kernel<<<N_NODES / 8, 256, 0, stream>>>(Bbuf, csr, row_off, dinv, wbuf + OW_bc2, Abuf);
    // node head: z = relu(h2@Wn1+bn1) -> Bbuf (pitch 64); logits -> d_out
    gemm_rows<128, 64, true, true, false><<<gB, 256, 0, stream>>>(Abuf, N_NODES, wbuf + OW_Wn1, 64, wbuf + OW_bn1, Bbuf, 64, nullptr, nullptr, nullptr);
    gemm_rows<64, 16, false, true, false><<<gB, 256, 0, stream>>>(Bbuf, N_NODES, wbuf + OW_Wn2, 12, wbuf + OW_bn2, d_out, 12, nullptr, nullptr, dtflag);
    // edge head precompute (dual, permuted): P -> Bbuf, Q -> Abuf (in-place safe)
    gemm_pq<<<gB, 256, 0, stream>>>(Abuf, N_NODES, wbuf + OW_We1, wbuf + OW_We1 + 128 * 128, Bbuf, Abuf);
    // fused edge head: 128 edges per block
    edge_head<<<(N_EDGES + 127) / 128, 256, 0, stream>>>(ea, erow, ecol, Bbuf, Abuf, wbuf, d_out, dtflag);
}

// Round 7
// 538.761 us; speedup vs baseline: 1.3014x; 1.0385x over previous
//
#include <hip/hip_runtime.h>

#define N_NODES 100000
#define N_EDGES 1000000
#define NB_SCAN 391  /* ceil(N/256) */
#define EDGE_OUT_BASE 1200000  /* N_NODES*12 elements */

typedef __attribute__((ext_vector_type(8))) short short8;
typedef __attribute__((ext_vector_type(4))) unsigned short us4;
typedef __attribute__((ext_vector_type(4))) float f32x4;

__device__ __forceinline__ float bf2f(unsigned short u) {
    unsigned int x = ((unsigned int)u) << 16;
    return __builtin_bit_cast(float, x);
}
__device__ __forceinline__ float lo_bf(unsigned int u) {
    return __builtin_bit_cast(float, u << 16);
}
__device__ __forceinline__ float hi_bf(unsigned int u) {
    return __builtin_bit_cast(float, u & 0xffff0000u);
}
__device__ __forceinline__ unsigned short f2bf(float f) {
    unsigned int x = __builtin_bit_cast(unsigned int, f);
    return (unsigned short)((x + 0x7fffu + ((x >> 16) & 1u)) >> 16);
}

// ---------------- dtype detection ----------------
__global__ __launch_bounds__(256) void k_detect(const unsigned short* __restrict__ xr,
                                                int* __restrict__ flag) {
    __shared__ int s[256];
    int t = threadIdx.x;
    int cnt = 0;
    for (int i = t; i < 8192; i += 256) {
        int e = (xr[i] >> 7) & 0xFF;
        if (e >= 148) cnt++;
    }
    s[t] = cnt;
    __syncthreads();
    for (int off = 128; off > 0; off >>= 1) {
        if (t < off) s[t] += s[t + off];
        __syncthreads();
    }
    if (t == 0) *flag = (s[0] > 100) ? 1 : 0;
}

// ---------------- weight canonicalization (any dtype -> bf16) ----------------
struct WPack { const void* p[14]; };
#define W_TOTAL 87888
__global__ __launch_bounds__(256) void k_convw(WPack wp, const int* __restrict__ flag,
                                               unsigned short* __restrict__ dst) {
    const int starts[15] = {0, 8192, 8320, 24704, 24832, 41216, 41344, 49536,
                            49600, 50368, 50380, 87244, 87372, 87884, 87888};
    bool f32 = (*flag != 0);
    int i = blockIdx.x * 256 + threadIdx.x;
    if (i >= W_TOTAL) return;
    int s = 0;
#pragma unroll
    for (int k = 1; k < 14; k++) s += (i >= starts[k]) ? 1 : 0;
    int j = i - starts[s];
    dst[i] = f32 ? f2bf(((const float*)wp.p[s])[j]) : ((const unsigned short*)wp.p[s])[j];
}
#define OW_We 0
#define OW_be 8192
#define OW_Wc1 8320
#define OW_bc1 24704
#define OW_Wc2 24832
#define OW_bc2 41216
#define OW_Wn1 41344
#define OW_bn1 49536
#define OW_Wn2 49600
#define OW_bn2 50368
#define OW_We1 50380
#define OW_be1 87244
#define OW_We2 87372
#define OW_be2 87884

// ---------------- graph build ----------------
__global__ __launch_bounds__(256) void k_hist(const int* __restrict__ ecol, int* __restrict__ deg) {
    int e = blockIdx.x * 256 + threadIdx.x;
    if (e < N_EDGES) atomicAdd(&deg[ecol[e]], 1);
}

__global__ __launch_bounds__(256) void k_scanA(const int* __restrict__ deg, int* __restrict__ bsum) {
    __shared__ int s[256];
    int i = blockIdx.x * 256 + threadIdx.x;
    s[threadIdx.x] = (i < N_NODES) ? deg[i] : 0;
    __syncthreads();
    for (int off = 128; off > 0; off >>= 1) {
        if (threadIdx.x < off) s[threadIdx.x] += s[threadIdx.x + off];
        __syncthreads();
    }
    if (threadIdx.x == 0) bsum[blockIdx.x] = s[0];
}

__global__ __launch_bounds__(512) void k_scanB(int* __restrict__ bsum) {
    __shared__ int s[512];
    int t = threadIdx.x;
    int v = (t < NB_SCAN) ? bsum[t] : 0;
    s[t] = v;
    __syncthreads();
    for (int off = 1; off < 512; off <<= 1) {
        int x = (t >= off) ? s[t - off] : 0;
        __syncthreads();
        s[t] += x;
        __syncthreads();
    }
    if (t < NB_SCAN) bsum[t] = s[t] - v;  // exclusive
}

__global__ __launch_bounds__(256) void k_scanC(const int* __restrict__ deg, const int* __restrict__ bsum,
                                               int* __restrict__ row_off, int* __restrict__ cursor,
                                               float* __restrict__ dinv) {
    __shared__ int s[256];
    int i = blockIdx.x * 256 + threadIdx.x;
    int t = threadIdx.x;
    int v = (i < N_NODES) ? deg[i] : 0;
    s[t] = v;
    __syncthreads();
    for (int off = 1; off < 256; off <<= 1) {
        int x = (t >= off) ? s[t - off] : 0;
        __syncthreads();
        s[t] += x;
        __syncthreads();
    }
    int excl = s[t] - v + bsum[blockIdx.x];
    if (i < N_NODES) {
        row_off[i] = excl;
        cursor[i] = excl;
        dinv[i] = rsqrtf((float)(v + 1));  // +1 self-loop
    }
    if (i == N_NODES - 1) row_off[N_NODES] = excl + v;
}

__global__ __launch_bounds__(256) void k_fill(const int* __restrict__ erow, const int* __restrict__ ecol,
                                              int* __restrict__ cursor, int* __restrict__ csr) {
    int e = blockIdx.x * 256 + threadIdx.x;
    if (e < N_EDGES) {
        int pos = atomicAdd(&cursor[ecol[e]], 1);
        csr[pos] = erow[e];
    }
}

// ---------------- rows GEMM: Out[M,o_real] = act(A[M,K] @ W[K,o_real] + bias) [* rowscale] ----------------
template <int K, int O, bool RELU, bool BIAS, bool SCALE>
__global__ __launch_bounds__(256) void gemm_rows(const void* __restrict__ A, int M,
                                                 const unsigned short* __restrict__ W, int o_real,
                                                 const unsigned short* __restrict__ bias,
                                                 void* __restrict__ Out, int out_pitch,
                                                 const float* __restrict__ rowscale,
                                                 const int* aflag, const int* oflag) {
    constexpr int KP = K + 8;
    constexpr int KS = K / 32;
    constexpr int OT = O / 16;
    __shared__ short wt[O * KP];
    __shared__ float bias_s[O];
    int tid = threadIdx.x;
    for (int idx = tid; idx < K * O; idx += 256) {
        int k = idx / O, o = idx % O;
        short w = 0;
        if (o < o_real) w = (short)W[(size_t)k * o_real + o];
        wt[o * KP + k] = w;
    }
    if (BIAS) {
        for (int o = tid; o < O; o += 256) bias_s[o] = (o < o_real) ? bf2f(bias[o]) : 0.f;
    }
    __syncthreads();

    bool af32 = aflag && (*aflag != 0);
    bool of32 = oflag && (*oflag != 0);

    int wid = tid >> 6, lane = tid & 63;
    int rbase = (blockIdx.x * 4 + wid) * 32;
    if (rbase >= M) return;
    int lq = lane >> 4, lr = lane & 15;

    short8 a[2][KS];
#pragma unroll
    for (int rg = 0; rg < 2; rg++) {
        int row = rbase + rg * 16 + lr;
        if (row >= M) row = M - 1;
        if (af32) {
            const float* ap = (const float*)A + (size_t)row * K + lq * 8;
#pragma unroll
            for (int ks = 0; ks < KS; ks++) {
                f32x4 u0 = *(const f32x4*)(ap + ks * 32);
                f32x4 u1 = *(const f32x4*)(ap + ks * 32 + 4);
                short8 v;
                v[0] = (short)f2bf(u0[0]); v[1] = (short)f2bf(u0[1]);
                v[2] = (short)f2bf(u0[2]); v[3] = (short)f2bf(u0[3]);
                v[4] = (short)f2bf(u1[0]); v[5] = (short)f2bf(u1[1]);
                v[6] = (short)f2bf(u1[2]); v[7] = (short)f2bf(u1[3]);
                a[rg][ks] = v;
            }
        } else {
            const unsigned short* ap = (const unsigned short*)A + (size_t)row * K + lq * 8;
#pragma unroll
            for (int ks = 0; ks < KS; ks++) a[rg][ks] = *(const short8*)(ap + ks * 32);
        }
    }

    f32x4 acc[2][OT];
#pragma unroll
    for (int rg = 0; rg < 2; rg++)
#pragma unroll
        for (int j = 0; j < OT; j++) {
            acc[rg][j][0] = 0.f; acc[rg][j][1] = 0.f; acc[rg][j][2] = 0.f; acc[rg][j][3] = 0.f;
        }

#pragma unroll
    for (int j = 0; j < OT; j++) {
        short8 b[KS];
#pragma unroll
        for (int ks = 0; ks < KS; ks++)
            b[ks] = *(const short8*)(&wt[(lr + 16 * j) * KP + ks * 32 + lq * 8]);
#pragma unroll
        for (int rg = 0; rg < 2; rg++)
#pragma unroll
            for (int ks = 0; ks < KS; ks++)
                acc[rg][j] = __builtin_amdgcn_mfma_f32_16x16x32_bf16(a[rg][ks], b[ks], acc[rg][j], 0, 0, 0);
    }

    // D layout: col = lane&15, row = (lane>>4)*4 + reg
#pragma unroll
    for (int rg = 0; rg < 2; rg++)
#pragma unroll
        for (int j = 0; j < OT; j++)
#pragma unroll
            for (int r = 0; r < 4; r++) {
                int row = rbase + rg * 16 + lq * 4 + r;
                int col = lr + 16 * j;
                if (row < M && col < o_real) {
                    float v = acc[rg][j][r];
                    if (BIAS) v += bias_s[col];
                    if (RELU) v = fmaxf(v, 0.f);
                    if (SCALE) v *= rowscale[row];
                    size_t oi = (size_t)row * out_pitch + col;
                    if (of32) ((float*)Out)[oi] = v;
                    else ((unsigned short*)Out)[oi] = f2bf(v);
                }
            }
}

// ---------------- fused node head: logits = relu(h2@Wn1+bn1)@Wn2+bn2 ----------------
__global__ __launch_bounds__(256) void node_head(const unsigned short* __restrict__ A, int M,
                                                 const unsigned short* __restrict__ wbuf,
                                                 void* __restrict__ Out, const int* oflag) {
    __shared__ short wt1[64 * 136];  // Wn1^T [o][k], K=128
    __shared__ short zb[128 * 72];   // z[row][k], K=64, pitch 72
    __shared__ short wt2[16 * 72];   // Wn2^T [o][k], K=64 (12 real)
    __shared__ float b1[64];
    __shared__ float b2[16];
    int tid = threadIdx.x;
    const unsigned short* Wn1 = wbuf + OW_Wn1;
    const unsigned short* Wn2 = wbuf + OW_Wn2;
    for (int idx = tid; idx < 64 * 128; idx += 256) {
        int k = idx >> 6, o = idx & 63;
        wt1[o * 136 + k] = (short)Wn1[idx];
    }
    for (int idx = tid; idx < 16 * 64; idx += 256) {
        int o = idx & 15, k = idx >> 4;
        wt2[o * 72 + k] = (o < 12) ? (short)Wn2[k * 12 + o] : 0;
    }
    if (tid < 64) b1[tid] = bf2f(wbuf[OW_bn1 + tid]);
    if (tid < 16) b2[tid] = (tid < 12) ? bf2f(wbuf[OW_bn2 + tid]) : 0.f;
    __syncthreads();

    bool of32 = oflag && (*oflag != 0);
    int wid = tid >> 6, lane = tid & 63;
    int lq = lane >> 4, lr = lane & 15;
    int rbase = blockIdx.x * 128 + wid * 32;

    // A-frags K=128
    short8 a[2][4];
#pragma unroll
    for (int rg = 0; rg < 2; rg++) {
        int row = rbase + rg * 16 + lr;
        if (row >= M) row = M - 1;
        const unsigned short* ap = A + (size_t)row * 128 + lq * 8;
#pragma unroll
        for (int ks = 0; ks < 4; ks++) a[rg][ks] = *(const short8*)(ap + ks * 32);
    }

    // phase 1: z = relu(A@Wn1 + bn1), O=64 (OT=4)
    {
        f32x4 acc[2][4];
#pragma unroll
        for (int rg = 0; rg < 2; rg++)
#pragma unroll
            for (int j = 0; j < 4; j++) {
                acc[rg][j][0] = 0.f; acc[rg][j][1] = 0.f; acc[rg][j][2] = 0.f; acc[rg][j][3] = 0.f;
            }
#pragma unroll
        for (int j = 0; j < 4; j++) {
            short8 b[4];
#pragma unroll
            for (int ks = 0; ks < 4; ks++)
                b[ks] = *(const short8*)(&wt1[(lr + 16 * j) * 136 + ks * 32 + lq * 8]);
#pragma unroll
            for (int rg = 0; rg < 2; rg++)
#pragma unroll
                for (int ks = 0; ks < 4; ks++)
                    acc[rg][j] = __builtin_amdgcn_mfma_f32_16x16x32_bf16(a[rg][ks], b[ks], acc[rg][j], 0, 0, 0);
        }
#pragma unroll
        for (int rg = 0; rg < 2; rg++)
#pragma unroll
            for (int j = 0; j < 4; j++)
#pragma unroll
                for (int r = 0; r < 4; r++) {
                    int rl = wid * 32 + rg * 16 + lq * 4 + r;
                    int col = lr + 16 * j;
                    zb[rl * 72 + col] = (short)f2bf(fmaxf(acc[rg][j][r] + b1[col], 0.f));
                }
    }
    __syncthreads();

    // phase 2: logits = z@Wn2 + bn2, K=64, O=16 (12 real)
    {
        short8 a2[2][2];
#pragma unroll
        for (int rg = 0; rg < 2; rg++) {
            int rl = wid * 32 + rg * 16 + lr;
#pragma unroll
            for (int ks = 0; ks < 2; ks++)
                a2[rg][ks] = *(const short8*)(&zb[rl * 72 + ks * 32 + lq * 8]);
        }
        short8 b[2];
#pragma unroll
        for (int ks = 0; ks < 2; ks++)
            b[ks] = *(const short8*)(&wt2[lr * 72 + ks * 32 + lq * 8]);
        f32x4 acc[2];
#pragma unroll
        for (int rg = 0; rg < 2; rg++) {
            acc[rg][0] = 0.f; acc[rg][1] = 0.f; acc[rg][2] = 0.f; acc[rg][3] = 0.f;
#pragma unroll
            for (int ks = 0; ks < 2; ks++)
                acc[rg] = __builtin_amdgcn_mfma_f32_16x16x32_bf16(a2[rg][ks], b[ks], acc[rg], 0, 0, 0);
        }
#pragma unroll
        for (int rg = 0; rg < 2; rg++)
#pragma unroll
            for (int r = 0; r < 4; r++) {
                int row = rbase + rg * 16 + lq * 4 + r;
                int col = lr;
                if (row < M && col < 12) {
                    float v = acc[rg][r] + b2[col];
                    size_t oi = (size_t)row * 12 + col;
                    if (of32) ((float*)Out)[oi] = v;
                    else ((unsigned short*)Out)[oi] = f2bf(v);
                }
            }
    }
}

// ---------------- dual GEMM for edge-head P/Q — PERMUTED channel layout ----------------
__global__ __launch_bounds__(256) void gemm_pq(const unsigned short* __restrict__ A, int M,
                                               const unsigned short* __restrict__ W1,
                                               const unsigned short* __restrict__ W2,
                                               unsigned short* __restrict__ Pout,
                                               unsigned short* __restrict__ Qout) {
    __shared__ short wt[128 * 136];
    int tid = threadIdx.x;
    int wid = tid >> 6, lane = tid & 63;
    int rbase = (blockIdx.x * 4 + wid) * 32;
    int lq = lane >> 4, lr = lane & 15;

    // A fragments (loaded once, before ANY store)
    short8 a[2][4];
#pragma unroll
    for (int rg = 0; rg < 2; rg++) {
        int row = rbase + rg * 16 + lr;
        if (row >= M) row = M - 1;
        const unsigned short* ap = A + (size_t)row * 128 + lq * 8;
#pragma unroll
        for (int ks = 0; ks < 4; ks++) a[rg][ks] = *(const short8*)(ap + ks * 32);
    }

    // col = lr + 16j -> permuted position = (lr>>2)*32 + j*4 + (lr&3)
    int pc0 = (lr >> 2) * 32 + (lr & 3);

    // ---- phase P ----
    for (int idx = tid; idx < 128 * 128; idx += 256) {
        int k = idx >> 7, o = idx & 127;
        wt[o * 136 + k] = (short)W1[idx];
    }
    __syncthreads();
    {
        f32x4 acc[2][8];
#pragma unroll
        for (int rg = 0; rg < 2; rg++)
#pragma unroll
            for (int j = 0; j < 8; j++) {
                acc[rg][j][0] = 0.f; acc[rg][j][1] = 0.f; acc[rg][j][2] = 0.f; acc[rg][j][3] = 0.f;
            }
#pragma unroll
        for (int j = 0; j < 8; j++) {
            short8 b[4];
#pragma unroll
            for (int ks = 0; ks < 4; ks++)
                b[ks] = *(const short8*)(&wt[(lr + 16 * j) * 136 + ks * 32 + lq * 8]);
#pragma unroll
            for (int rg = 0; rg < 2; rg++)
#pragma unroll
                for (int ks = 0; ks < 4; ks++)
                    acc[rg][j] = __builtin_amdgcn_mfma_f32_16x16x32_bf16(a[rg][ks], b[ks], acc[rg][j], 0, 0, 0);
        }
#pragma unroll
        for (int rg = 0; rg < 2; rg++)
#pragma unroll
            for (int j = 0; j < 8; j++)
#pragma unroll
                for (int r = 0; r < 4; r++) {
                    int row = rbase + rg * 16 + lq * 4 + r;
                    if (row < M) Pout[(size_t)row * 128 + pc0 + j * 4] = f2bf(acc[rg][j][r]);
                }
    }
    __syncthreads();

    // ---- phase Q ----
    for (int idx = tid; idx < 128 * 128; idx += 256) {
        int k = idx >> 7, o = idx & 127;
        wt[o * 136 + k] = (short)W2[idx];
    }
    __syncthreads();
    {
        f32x4 acc[2][8];
#pragma unroll
        for (int rg = 0; rg < 2; rg++)
#pragma unroll
            for (int j = 0; j < 8; j++) {
                acc[rg][j][0] = 0.f; acc[rg][j][1] = 0.f; acc[rg][j][2] = 0.f; acc[rg][j][3] = 0.f;
            }
#pragma unroll
        for (int j = 0; j < 8; j++) {
            short8 b[4];
#pragma unroll
            for (int ks = 0; ks < 4; ks++)
                b[ks] = *(const short8*)(&wt[(lr + 16 * j) * 136 + ks * 32 + lq * 8]);
#pragma unroll
            for (int rg = 0; rg < 2; rg++)
#pragma unroll
                for (int ks = 0; ks < 4; ks++)
                    acc[rg][j] = __builtin_amdgcn_mfma_f32_16x16x32_bf16(a[rg][ks], b[ks], acc[rg][j], 0, 0, 0);
        }
#pragma unroll
        for (int rg = 0; rg < 2; rg++)
#pragma unroll
            for (int j = 0; j < 8; j++)
#pragma unroll
                for (int r = 0; r < 4; r++) {
                    int row = rbase + rg * 16 + lq * 4 + r;
                    if (row < M) Qout[(size_t)row * 128 + pc0 + j * 4] = f2bf(acc[rg][j][r]);
                }
    }
}

// ---------------- GCN conv: 2 nodes/wave, dual unroll-4 gather streams ----------------
__global__ __launch_bounds__(256) void conv_kernel(const unsigned short* __restrict__ xw_s,
                                                   const int* __restrict__ csr_src,
                                                   const int* __restrict__ row_off,
                                                   const float* __restrict__ dinv,
                                                   const unsigned short* __restrict__ bias,
                                                   unsigned short* __restrict__ out) {
    int wid = threadIdx.x >> 6, lane = threadIdx.x & 63;
    int base = (blockIdx.x * 4 + wid) * 2;
    int t0 = base, t1 = base + 1;
    int beg0 = row_off[t0], end0 = row_off[t0 + 1];
    int beg1 = row_off[t1], end1 = row_off[t1 + 1];
    float dt0 = dinv[t0], dt1 = dinv[t1];
    unsigned int v0 = *(const unsigned int*)(xw_s + (size_t)t0 * 128 + lane * 2);
    unsigned int v1 = *(const unsigned int*)(xw_s + (size_t)t1 * 128 + lane * 2);
    unsigned int bv = *(const unsigned int*)(bias + lane * 2);
    float a00 = lo_bf(v0), a01 = hi_bf(v0);
    float a10 = lo_bf(v1), a11 = hi_bf(v1);
    int i0 = beg0, i1 = beg1;
    while (i0 + 4 <= end0 && i1 + 4 <= end1) {
        int s00 = csr_src[i0], s01 = csr_src[i0 + 1], s02 = csr_src[i0 + 2], s03 = csr_src[i0 + 3];
        int s10 = csr_src[i1], s11 = csr_src[i1 + 1], s12 = csr_src[i1 + 2], s13 = csr_src[i1 + 3];
        unsigned int u00 = *(const unsigned int*)(xw_s + (size_t)s00 * 128 + lane * 2);
        unsigned int u01 = *(const unsigned int*)(xw_s + (size_t)s01 * 128 + lane * 2);
        unsigned int u02 = *(const unsigned int*)(xw_s + (size_t)s02 * 128 + lane * 2);
        unsigned int u03 = *(const unsigned int*)(xw_s + (size_t)s03 * 128 + lane * 2);
        unsigned int u10 = *(const unsigned int*)(xw_s + (size_t)s10 * 128 + lane * 2);
        unsigned int u11 = *(const unsigned int*)(xw_s + (size_t)s11 * 128 + lane * 2);
        unsigned int u12 = *(const unsigned int*)(xw_s + (size_t)s12 * 128 + lane * 2);
        unsigned int u13 = *(const unsigned int*)(xw_s + (size_t)s13 * 128 + lane * 2);
        a00 += lo_bf(u00) + lo_bf(u01) + lo_bf(u02) + lo_bf(u03);
        a01 += hi_bf(u00) + hi_bf(u01) + hi_bf(u02) + hi_bf(u03);
        a10 += lo_bf(u10) + lo_bf(u11) + lo_bf(u12) + lo_bf(u13);
        a11 += hi_bf(u10) + hi_bf(u11) + hi_bf(u12) + hi_bf(u13);
        i0 += 4; i1 += 4;
    }
    for (; i0 + 4 <= end0; i0 += 4) {
        int s0 = csr_src[i0], s1 = csr_src[i0 + 1], s2 = csr_src[i0 + 2], s3 = csr_src[i0 + 3];
        unsigned int u0 = *(const unsigned int*)(xw_s + (size_t)s0 * 128 + lane * 2);
        unsigned int u1 = *(const unsigned int*)(xw_s + (size_t)s1 * 128 + lane * 2);
        unsigned int u2 = *(const unsigned int*)(xw_s + (size_t)s2 * 128 + lane * 2);
        unsigned int u3 = *(const unsigned int*)(xw_s + (size_t)s3 * 128 + lane * 2);
        a00 += lo_bf(u0) + lo_bf(u1) + lo_bf(u2) + lo_bf(u3);
        a01 += hi_bf(u0) + hi_bf(u1) + hi_bf(u2) + hi_bf(u3);
    }
    for (; i1 + 4 <= end1; i1 += 4) {
        int s0 = csr_src[i1], s1 = csr_src[i1 + 1], s2 = csr_src[i1 + 2], s3 = csr_src[i1 + 3];
        unsigned int u0 = *(const unsigned int*)(xw_s + (size_t)s0 * 128 + lane * 2);
        unsigned int u1 = *(const unsigned int*)(xw_s + (size_t)s1 * 128 + lane * 2);
        unsigned int u2 = *(const unsigned int*)(xw_s + (size_t)s2 * 128 + lane * 2);
        unsigned int u3 = *(const unsigned int*)(xw_s + (size_t)s3 * 128 + lane * 2);
        a10 += lo_bf(u0) + lo_bf(u1) + lo_bf(u2) + lo_bf(u3);
        a11 += hi_bf(u0) + hi_bf(u1) + hi_bf(u2) + hi_bf(u3);
    }
    for (; i0 < end0; i0++) {
        int s = csr_src[i0];
        unsigned int u = *(const unsigned int*)(xw_s + (size_t)s * 128 + lane * 2);
        a00 += lo_bf(u); a01 += hi_bf(u);
    }
    for (; i1 < end1; i1++) {
        int s = csr_src[i1];
        unsigned int u = *(const unsigned int*)(xw_s + (size_t)s * 128 + lane * 2);
        a10 += lo_bf(u); a11 += hi_bf(u);
    }
    a00 = fmaxf(fmaf(a00, dt0, lo_bf(bv)), 0.f);
    a01 = fmaxf(fmaf(a01, dt0, hi_bf(bv)), 0.f);
    a10 = fmaxf(fmaf(a10, dt1, lo_bf(bv)), 0.f);
    a11 = fmaxf(fmaf(a11, dt1, hi_bf(bv)), 0.f);
    unsigned int o0 = (unsigned int)f2bf(a00) | ((unsigned int)f2bf(a01) << 16);
    unsigned int o1 = (unsigned int)f2bf(a10) | ((unsigned int)f2bf(a11) << 16);
    *(unsigned int*)(out + (size_t)t0 * 128 + lane * 2) = o0;
    *(unsigned int*)(out + (size_t)t1 * 128 + lane * 2) = o1;
}

// ---------------- edge head epilogue chunk helper ----------------
__device__ __forceinline__ void epi_chunk(f32x4& ov, const f32x4& acc_lo, const f32x4& acc_hi,
                                          short8 pv, short8 qv,
                                          const float* __restrict__ b1s,
                                          const float* __restrict__ w2s, int pb) {
#pragma unroll
    for (int jj = 0; jj < 2; jj++) {
        const f32x4& ac = jj ? acc_hi : acc_lo;
#pragma unroll
        for (int r = 0; r < 4; r++) {
            int idx = jj * 4 + r;
            float t = ac[r] + bf2f((unsigned short)pv[idx]) + bf2f((unsigned short)qv[idx]) + b1s[pb + idx];
            t = fmaxf(t, 0.f);
            f32x4 w2v = *(const f32x4*)(&w2s[(pb + idx) * 4]);
            ov[0] = fmaf(t, w2v[0], ov[0]);
            ov[1] = fmaf(t, w2v[1], ov[1]);
            ov[2] = fmaf(t, w2v[2], ov[2]);
            ov[3] = fmaf(t, w2v[3], ov[3]);
        }
    }
}

// ---------------- fused edge head: swapped-MFMA + permuted P/Q, two-half (low reg pressure) ----------------
__global__ __launch_bounds__(256) void edge_head(const void* __restrict__ ea,
                                                 const int* __restrict__ erow, const int* __restrict__ ecol,
                                                 const unsigned short* __restrict__ P,
                                                 const unsigned short* __restrict__ Q,
                                                 const unsigned short* __restrict__ wbuf,
                                                 void* __restrict__ out, const int* dtflag) {
    __shared__ short wct[128 * 40];  // Wc3^T [ch][k], pitch 40
    __shared__ float w2s[128 * 4];   // permuted
    __shared__ float b1s[128];       // permuted
    int tid = threadIdx.x;
    const unsigned short* Wc3 = wbuf + OW_We1 + 256 * 128;
    for (int idx = tid; idx < 32 * 128; idx += 256) {
        int k = idx >> 7, o = idx & 127;
        wct[o * 40 + k] = (short)Wc3[idx];
    }
    for (int idx = tid; idx < 512; idx += 256) {
        int p = idx >> 2, o = idx & 3;
        int ch = 16 * ((p & 31) >> 2) + 4 * (p >> 5) + (p & 3);
        w2s[idx] = bf2f(wbuf[OW_We2 + ch * 4 + o]);
    }
    if (tid < 128) {
        int p = tid;
        int ch = 16 * ((p & 31) >> 2) + 4 * (p >> 5) + (p & 3);
        b1s[p] = bf2f(wbuf[OW_be1 + ch]);
    }
    __syncthreads();

    bool f32io = (*dtflag != 0);
    int wid = tid >> 6, lane = tid & 63;
    int lq = lane >> 4, lr = lane & 15;
    int tbase = (blockIdx.x * 4 + wid) * 2;
    int e0a = tbase * 16, e0b = e0a + 16;

    int gea = e0a + lr, geb = e0b + lr;
    bool va = gea < N_EDGES, vb = geb < N_EDGES;
    int geca = va ? gea : (N_EDGES - 1);
    int gecb = vb ? geb : (N_EDGES - 1);

    int rna = erow[geca], cna = ecol[geca];
    int rnb = erow[gecb], cnb = ecol[gecb];

    auto load_efrag = [&](int ge) -> short8 {
        short8 v;
        if (f32io) {
            const float* eap = (const float*)ea + (size_t)ge * 32 + lq * 8;
            f32x4 u0 = *(const f32x4*)eap;
            f32x4 u1 = *(const f32x4*)(eap + 4);
            v[0] = (short)f2bf(u0[0]); v[1] = (short)f2bf(u0[1]);
            v[2] = (short)f2bf(u0[2]); v[3] = (short)f2bf(u0[3]);
            v[4] = (short)f2bf(u1[0]); v[5] = (short)f2bf(u1[1]);
            v[6] = (short)f2bf(u1[2]); v[7] = (short)f2bf(u1[3]);
        } else {
            v = *(const short8*)((const unsigned short*)ea + (size_t)ge * 32 + lq * 8);
        }
        return v;
    };
    short8 efA = load_efrag(geca);
    short8 efB = load_efrag(gecb);

    const unsigned short* PpA = P + (size_t)rna * 128 + lq * 32;
    const unsigned short* QpA = Q + (size_t)cna * 128 + lq * 32;
    const unsigned short* PpB = P + (size_t)rnb * 128 + lq * 32;
    const unsigned short* QpB = Q + (size_t)cnb * 128 + lq * 32;

    f32x4 zero; zero[0] = 0.f; zero[1] = 0.f; zero[2] = 0.f; zero[3] = 0.f;
    f32x4 ovA = zero, ovB = zero;

    // ---- half 0: channels 0..63 (j=0..3, chunks c=0,1) ----
    {
        short8 pA0 = *(const short8*)(PpA + 0);
        short8 pA1 = *(const short8*)(PpA + 8);
        short8 qA0 = *(const short8*)(QpA + 0);
        short8 qA1 = *(const short8*)(QpA + 8);
        short8 pB0 = *(const short8*)(PpB + 0);
        short8 pB1 = *(const short8*)(PpB + 8);
        short8 qB0 = *(const short8*)(QpB + 0);
        short8 qB1 = *(const short8*)(QpB + 8);
        short8 wf0 = *(const short8*)(&wct[(0 * 16 + lr) * 40 + lq * 8]);
        short8 wf1 = *(const short8*)(&wct[(1 * 16 + lr) * 40 + lq * 8]);
        short8 wf2 = *(const short8*)(&wct[(2 * 16 + lr) * 40 + lq * 8]);
        short8 wf3 = *(const short8*)(&wct[(3 * 16 + lr) * 40 + lq * 8]);
        f32x4 aA0 = __builtin_amdgcn_mfma_f32_16x16x32_bf16(wf0, efA, zero, 0, 0, 0);
        f32x4 aA1 = __builtin_amdgcn_mfma_f32_16x16x32_bf16(wf1, efA, zero, 0, 0, 0);
        f32x4 aA2 = __builtin_amdgcn_mfma_f32_16x16x32_bf16(wf2, efA, zero, 0, 0, 0);
        f32x4 aA3 = __builtin_amdgcn_mfma_f32_16x16x32_bf16(wf3, efA, zero, 0, 0, 0);
        f32x4 aB0 = __builtin_amdgcn_mfma_f32_16x16x32_bf16(wf0, efB, zero, 0, 0, 0);
        f32x4 aB1 = __builtin_amdgcn_mfma_f32_16x16x32_bf16(wf1, efB, zero, 0, 0, 0);
        f32x4 aB2 = __builtin_amdgcn_mfma_f32_16x16x32_bf16(wf2, efB, zero, 0, 0, 0);
        f32x4 aB3 = __builtin_amdgcn_mfma_f32_16x16x32_bf16(wf3, efB, zero, 0, 0, 0);
        epi_chunk(ovA, aA0, aA1, pA0, qA0, b1s, w2s, lq * 32 + 0);
        epi_chunk(ovA, aA2, aA3, pA1, qA1, b1s, w2s, lq * 32 + 8);
        epi_chunk(ovB, aB0, aB1, pB0, qB0, b1s, w2s, lq * 32 + 0);
        epi_chunk(ovB, aB2, aB3, pB1, qB1, b1s, w2s, lq * 32 + 8);
    }
    // ---- half 1: channels 64..127 (j=4..7, chunks c=2,3) ----
    {
        short8 pA0 = *(const short8*)(PpA + 16);
        short8 pA1 = *(const short8*)(PpA + 24);
        short8 qA0 = *(const short8*)(QpA + 16);
        short8 qA1 = *(const short8*)(QpA + 24);
        short8 pB0 = *(const short8*)(PpB + 16);
        short8 pB1 = *(const short8*)(PpB + 24);
        short8 qB0 = *(const short8*)(QpB + 16);
        short8 qB1 = *(const short8*)(QpB + 24);
        short8 wf0 = *(const short8*)(&wct[(4 * 16 + lr) * 40 + lq * 8]);
        short8 wf1 = *(const short8*)(&wct[(5 * 16 + lr) * 40 + lq * 8]);
        short8 wf2 = *(const short8*)(&wct[(6 * 16 + lr) * 40 + lq * 8]);
        short8 wf3 = *(const short8*)(&wct[(7 * 16 + lr) * 40 + lq * 8]);
        f32x4 aA0 = __builtin_amdgcn_mfma_f32_16x16x32_bf16(wf0, efA, zero, 0, 0, 0);
        f32x4 aA1 = __builtin_amdgcn_mfma_f32_16x16x32_bf16(wf1, efA, zero, 0, 0, 0);
        f32x4 aA2 = __builtin_amdgcn_mfma_f32_16x16x32_bf16(wf2, efA, zero, 0, 0, 0);
        f32x4 aA3 = __builtin_amdgcn_mfma_f32_16x16x32_bf16(wf3, efA, zero, 0, 0, 0);
        f32x4 aB0 = __builtin_amdgcn_mfma_f32_16x16x32_bf16(wf0, efB, zero, 0, 0, 0);
        f32x4 aB1 = __builtin_amdgcn_mfma_f32_16x16x32_bf16(wf1, efB, zero, 0, 0, 0);
        f32x4 aB2 = __builtin_amdgcn_mfma_f32_16x16x32_bf16(wf2, efB, zero, 0, 0, 0);
        f32x4 aB3 = __builtin_amdgcn_mfma_f32_16x16x32_bf16(wf3, efB, zero, 0, 0, 0);
        epi_chunk(ovA, aA0, aA1, pA0, qA0, b1s, w2s, lq * 32 + 16);
        epi_chunk(ovA, aA2, aA3, pA1, qA1, b1s, w2s, lq * 32 + 24);
        epi_chunk(ovB, aB0, aB1, pB0, qB0, b1s, w2s, lq * 32 + 16);
        epi_chunk(ovB, aB2, aB3, pB1, qB1, b1s, w2s, lq * 32 + 24);
    }

    // reduce across lq (lane bits 4,5)
#pragma unroll
    for (int c = 0; c < 4; c++) {
        ovA[c] += __shfl_xor(ovA[c], 16);
        ovA[c] += __shfl_xor(ovA[c], 32);
        ovB[c] += __shfl_xor(ovB[c], 16);
        ovB[c] += __shfl_xor(ovB[c], 32);
    }
    if (lq == 0) {
        float be2_0 = bf2f(wbuf[OW_be2 + 0]), be2_1 = bf2f(wbuf[OW_be2 + 1]);
        float be2_2 = bf2f(wbuf[OW_be2 + 2]), be2_3 = bf2f(wbuf[OW_be2 + 3]);
        if (va) {
            size_t oi = (size_t)EDGE_OUT_BASE + (size_t)gea * 4;
            if (f32io) {
                f32x4 res; res[0] = ovA[0] + be2_0; res[1] = ovA[1] + be2_1;
                res[2] = ovA[2] + be2_2; res[3] = ovA[3] + be2_3;
                *(f32x4*)((float*)out + oi) = res;
            } else {
                us4 res; res[0] = f2bf(ovA[0] + be2_0); res[1] = f2bf(ovA[1] + be2_1);
                res[2] = f2bf(ovA[2] + be2_2); res[3] = f2bf(ovA[3] + be2_3);
                *(us4*)((unsigned short*)out + oi) = res;
            }
        }
        if (vb) {
            size_t oi = (size_t)EDGE_OUT_BASE + (size_t)geb * 4;
            if (f32io) {
                f32x4 res; res[0] = ovB[0] + be2_0; res[1] = ovB[1] + be2_1;
                res[2] = ovB[2] + be2_2; res[3] = ovB[3] + be2_3;
                *(f32x4*)((float*)out + oi) = res;
            } else {
                us4 res; res[0] = f2bf(ovB[0] + be2_0); res[1] = f2bf(ovB[1] + be2_1);
                res[2] = f2bf(ovB[2] + be2_2); res[3] = f2bf(ovB[3] + be2_3);
                *(us4*)((unsigned short*)out + oi) = res;
            }
        }
    }
}

// ---------------- launcher ----------------
extern "C" void kernel_launch(void* const* d_in, const int* in_sizes, int n_in,
                              void* d_out, int out_size, void* d_ws, size_t ws_size,
                              hipStream_t stream) {
    const void* x = d_in[0];
    const int* ei = (const int*)d_in[1];
    const void* ea = d_in[2];
    const int* erow = ei;
    const int* ecol = ei + N_EDGES;

    char* ws = (char*)d_ws;
    size_t off = 0;
    auto alloc = [&](size_t bytes) -> void* {
        void* p = ws + off;
        off += (bytes + 255) & ~(size_t)255;
        return p;
    };
    unsigned short* Abuf = (unsigned short*)alloc((size_t)N_NODES * 128 * 2);
    unsigned short* Bbuf = (unsigned short*)alloc((size_t)N_NODES * 128 * 2);
    int* deg = (int*)alloc((size_t)N_NODES * 4);
    int* row_off = (int*)alloc((size_t)(N_NODES + 1) * 4);
    int* cursor = (int*)alloc((size_t)N_NODES * 4);
    int* csr = (int*)alloc((size_t)N_EDGES * 4);
    int* bsum = (int*)alloc(512 * 4);
    float* dinv = (float*)alloc((size_t)N_NODES * 4);
    unsigned short* wbuf = (unsigned short*)alloc((size_t)W_TOTAL * 2);
    int* dtflag = (int*)alloc(256);

    // 1. dtype detection (device-side)
    k_detect<<<1, 256, 0, stream>>>((const unsigned short*)x, dtflag);

    // 2. canonicalize weights to bf16
    WPack wp;
    for (int i = 0; i < 14; i++) wp.p[i] = d_in[3 + i];
    k_convw<<<(W_TOTAL + 255) / 256, 256, 0, stream>>>(wp, dtflag, wbuf);

    // 3. graph build
    (void)hipMemsetAsync(deg, 0, (size_t)N_NODES * 4, stream);
    k_hist<<<(N_EDGES + 255) / 256, 256, 0, stream>>>(ecol, deg);
    k_scanA<<<NB_SCAN, 256, 0, stream>>>(deg, bsum);
    k_scanB<<<1, 512, 0, stream>>>(bsum);
    k_scanC<<<NB_SCAN, 256, 0, stream>>>(deg, bsum, row_off, cursor, dinv);
    k_fill<<<(N_EDGES + 255) / 256, 256, 0, stream>>>(erow, ecol, cursor, csr);

    int gB = (N_NODES + 127) / 128;
    // embed: h0 = relu(x@We+be) -> Abuf
    gemm_rows<64, 128, true, true, false><<<gB, 256, 0, stream>>>(x, N_NODES, wbuf + OW_We, 128, wbuf + OW_be, Abuf, 128, nullptr, dtflag, nullptr);
    // xw1_scaled = (h0@Wc1) * dinv[row] -> Bbuf
    gemm_rows<128, 128, false, false, true><<<gB, 256, 0, stream>>>(Abuf, N_NODES, wbuf + OW_Wc1, 128, nullptr, Bbuf, 128, dinv, nullptr, nullptr);
    conv_kernel<<<N_NODES / 8, 256, 0, stream>>>(Bbuf, csr, row_off, dinv, wbuf + OW_bc1, Abuf);
    // xw2_scaled = (h1@Wc2) * dinv[row] -> Bbuf
    gemm_rows<128, 128, false, false, true><<<gB, 256, 0, stream>>>(Abuf, N_NODES, wbuf + OW_Wc2, 128, nullptr, Bbuf, 128, dinv, nullptr, nullptr);
    conv_kernel<<<N_NODES / 8, 256, 0, stream>>>(Bbuf, csr, row_off, dinv, wbuf + OW_bc2, Abuf);
    // fused node head: logits -> d_out
    node_head<<<gB, 256, 0, stream>>>(Abuf, N_NODES, wbuf, d_out, dtflag);
    // edge head precompute (dual, permuted): P -> Bbuf, Q -> Abuf (in-place safe)
    gemm_pq<<<gB, 256, 0, stream>>>(Abuf, N_NODES, wbuf + OW_We1, wbuf + OW_We1 + 128 * 128, Bbuf, Abuf);
    // fused edge head: 128 edges per block
    edge_head<<<(N_EDGES + 127) / 128, 256, 0, stream>>>(ea, erow, ecol, Bbuf, Abuf, wbuf, d_out, dtflag);
}